// Round 1
// baseline (4364.803 us; speedup 1.0000x reference)
//
#include <hip/hip_runtime.h>
#include <cmath>

#define B_ 4
#define T_ 2048
#define C_ 1024
#define H_ 16
#define D_ 64
#define FF_ 4096
#define BT_ (B_ * T_)

// ---------------------------------------------------------------------------
// LayerNorm: one block per row (1024 floats), 256 threads, float4 loads.
// ---------------------------------------------------------------------------
__global__ __launch_bounds__(256) void ln_kernel(const float* __restrict__ x,
                                                 const float* __restrict__ g,
                                                 const float* __restrict__ b,
                                                 float* __restrict__ y) {
    __shared__ float ls[4], lq[4];
    __shared__ float mean_s, rstd_s;
    int row = blockIdx.x;
    const float4* xr = (const float4*)(x + (size_t)row * C_);
    float4 v = xr[threadIdx.x];
    float s = v.x + v.y + v.z + v.w;
    float sq = v.x * v.x + v.y * v.y + v.z * v.z + v.w * v.w;
#pragma unroll
    for (int off = 32; off > 0; off >>= 1) {
        s += __shfl_down(s, off);
        sq += __shfl_down(sq, off);
    }
    int wid = threadIdx.x >> 6, lane = threadIdx.x & 63;
    if (lane == 0) { ls[wid] = s; lq[wid] = sq; }
    __syncthreads();
    if (threadIdx.x == 0) {
        float S = ls[0] + ls[1] + ls[2] + ls[3];
        float Q = lq[0] + lq[1] + lq[2] + lq[3];
        float mean = S * (1.0f / C_);
        float var = Q * (1.0f / C_) - mean * mean;
        mean_s = mean;
        rstd_s = 1.0f / sqrtf(var + 1e-5f);
    }
    __syncthreads();
    float mean = mean_s, rstd = rstd_s;
    float4 gv = ((const float4*)g)[threadIdx.x];
    float4 bv = ((const float4*)b)[threadIdx.x];
    float4 o;
    o.x = (v.x - mean) * rstd * gv.x + bv.x;
    o.y = (v.y - mean) * rstd * gv.y + bv.y;
    o.z = (v.z - mean) * rstd * gv.z + bv.z;
    o.w = (v.w - mean) * rstd * gv.w + bv.w;
    ((float4*)(y + (size_t)row * C_))[threadIdx.x] = o;
}

// ---------------------------------------------------------------------------
// fp32 GEMM: C[M,N] = A[M,K] * W[N,K]^T (+bias, +gelu, +residual)
// Tiles: BM=BN=128, BK=16, 256 threads, each thread 8x8 outputs arranged as
// 2x2 blocks of 4x4 (contiguous float4 fragments -> <=2-way LDS conflicts).
// All M,N,K here are multiples of 128/128/16 -> no bounds checks.
// ---------------------------------------------------------------------------
template <int ACT, bool RES>
__global__ __launch_bounds__(256) void gemm_nt(const float* __restrict__ A,
                                               const float* __restrict__ W,
                                               const float* __restrict__ bias,
                                               const float* __restrict__ res,
                                               float* __restrict__ Cmat,
                                               int M, int N, int K) {
    __shared__ float As[16][128];
    __shared__ float Bs[16][128];
    int tid = threadIdx.x;
    int m0 = blockIdx.y * 128;
    int n0 = blockIdx.x * 128;
    int ty = tid >> 4, tx = tid & 15;
    int row = tid >> 2;       // 0..63
    int kq = (tid & 3) * 4;   // 0,4,8,12

    float acc[8][8];
#pragma unroll
    for (int i = 0; i < 8; ++i)
#pragma unroll
        for (int j = 0; j < 8; ++j) acc[i][j] = 0.0f;

    for (int k0 = 0; k0 < K; k0 += 16) {
        float4 a0 = *(const float4*)(A + (size_t)(m0 + row) * K + k0 + kq);
        float4 a1 = *(const float4*)(A + (size_t)(m0 + row + 64) * K + k0 + kq);
        float4 b0 = *(const float4*)(W + (size_t)(n0 + row) * K + k0 + kq);
        float4 b1 = *(const float4*)(W + (size_t)(n0 + row + 64) * K + k0 + kq);
        __syncthreads();  // previous tile fully consumed
        As[kq + 0][row] = a0.x; As[kq + 1][row] = a0.y;
        As[kq + 2][row] = a0.z; As[kq + 3][row] = a0.w;
        As[kq + 0][row + 64] = a1.x; As[kq + 1][row + 64] = a1.y;
        As[kq + 2][row + 64] = a1.z; As[kq + 3][row + 64] = a1.w;
        Bs[kq + 0][row] = b0.x; Bs[kq + 1][row] = b0.y;
        Bs[kq + 2][row] = b0.z; Bs[kq + 3][row] = b0.w;
        Bs[kq + 0][row + 64] = b1.x; Bs[kq + 1][row + 64] = b1.y;
        Bs[kq + 2][row + 64] = b1.z; Bs[kq + 3][row + 64] = b1.w;
        __syncthreads();
#pragma unroll
        for (int k = 0; k < 16; ++k) {
            float a[8], bb[8];
            *(float4*)&a[0] = *(const float4*)&As[k][ty * 4];
            *(float4*)&a[4] = *(const float4*)&As[k][64 + ty * 4];
            *(float4*)&bb[0] = *(const float4*)&Bs[k][tx * 4];
            *(float4*)&bb[4] = *(const float4*)&Bs[k][64 + tx * 4];
#pragma unroll
            for (int i = 0; i < 8; ++i)
#pragma unroll
                for (int j = 0; j < 8; ++j) acc[i][j] += a[i] * bb[j];
        }
    }

#pragma unroll
    for (int ia = 0; ia < 8; ++ia) {
        int mr = m0 + ((ia < 4) ? (ty * 4 + ia) : (64 + ty * 4 + (ia - 4)));
#pragma unroll
        for (int jh = 0; jh < 2; ++jh) {
            int nc = n0 + jh * 64 + tx * 4;
            float4 v;
            float* vp = &v.x;
#pragma unroll
            for (int jj = 0; jj < 4; ++jj) {
                float cv = acc[ia][jh * 4 + jj] + bias[nc + jj];
                if (ACT == 1) cv = 0.5f * cv * (1.0f + erff(cv * 0.70710678118654752f));
                if (RES) cv += res[(size_t)mr * N + nc + jj];
                vp[jj] = cv;
            }
            *(float4*)(Cmat + (size_t)mr * N + nc) = v;
        }
    }
}

// ---------------------------------------------------------------------------
// Flash attention fp32: block = 256 threads = 256 query rows of one (b,h).
// K/V tiles (64x64) staged in LDS; per-thread online softmax (no cross-lane).
// qkv layout: row bt, cols [0:1024)=q, [1024:2048)=k, [2048:3072)=v, head-major.
// ---------------------------------------------------------------------------
__global__ __launch_bounds__(256) void attn_kernel(const float* __restrict__ qkv,
                                                   float* __restrict__ o) {
    __shared__ float Ks[64][64];
    __shared__ float Vs[64][64];
    int bh = blockIdx.y;
    int bb = bh >> 4;
    int h = bh & 15;
    int t0 = blockIdx.x * 256;
    int qi = t0 + threadIdx.x;

    const float* qrow = qkv + (size_t)(bb * T_ + qi) * 3072 + h * 64;
    float q[64];
#pragma unroll
    for (int i = 0; i < 16; ++i) {
        float4 v = *(const float4*)(qrow + i * 4);
        q[i * 4 + 0] = v.x * 0.125f;  // 1/sqrt(64)
        q[i * 4 + 1] = v.y * 0.125f;
        q[i * 4 + 2] = v.z * 0.125f;
        q[i * 4 + 3] = v.w * 0.125f;
    }
    float acc[64];
#pragma unroll
    for (int d = 0; d < 64; ++d) acc[d] = 0.0f;
    float m = -INFINITY, l = 0.0f;

    int ntiles = (t0 >> 6) + 4;
    for (int tile = 0; tile < ntiles; ++tile) {
        int kt0 = tile << 6;
        __syncthreads();  // previous tile consumed
#pragma unroll
        for (int i = 0; i < 4; ++i) {
            int f4 = threadIdx.x + i * 256;
            int j = f4 >> 4;
            int d4 = (f4 & 15) * 4;
            const float* kp = qkv + (size_t)(bb * T_ + kt0 + j) * 3072 + 1024 + h * 64 + d4;
            float4 kv = *(const float4*)kp;
            float4 vv = *(const float4*)(kp + 1024);
            *(float4*)&Ks[j][d4] = kv;
            *(float4*)&Vs[j][d4] = vv;
        }
        __syncthreads();
        int jend = qi - kt0;
        if (jend > 63) jend = 63;
        for (int j = 0; j <= jend; ++j) {
            float s = 0.0f;
#pragma unroll
            for (int d = 0; d < 64; ++d) s = fmaf(q[d], Ks[j][d], s);
            if (s <= m) {
                float p = __expf(s - m);
                l += p;
#pragma unroll
                for (int d = 0; d < 64; ++d) acc[d] = fmaf(p, Vs[j][d], acc[d]);
            } else {
                float sc = __expf(m - s);
                m = s;
                l = fmaf(l, sc, 1.0f);
#pragma unroll
                for (int d = 0; d < 64; ++d) acc[d] = fmaf(acc[d], sc, Vs[j][d]);
            }
        }
    }
    float inv = 1.0f / l;
    float* orow = o + (size_t)(bb * T_ + qi) * 1024 + h * 64;
#pragma unroll
    for (int i = 0; i < 16; ++i) {
        float4 v;
        v.x = acc[i * 4 + 0] * inv;
        v.y = acc[i * 4 + 1] * inv;
        v.z = acc[i * 4 + 2] * inv;
        v.w = acc[i * 4 + 3] * inv;
        *(float4*)(orow + i * 4) = v;
    }
}

// ---------------------------------------------------------------------------
// Orchestration. Workspace layout (needs 128 MB):
//   wsA = ws+0      : 96 MB. Phase 1: qkv [8192,3072].
//                     Phase 2: h2 [8192,1024] (32MB) + ff chunk [4096,4096] (64MB)
//   wsB = ws+96MB   : 32 MB. Phase 1: ln1 out h [8192,1024]; then attn out o.
//   x1 (post-attn residual) lives in d_out; fc2 adds into it in place.
// ---------------------------------------------------------------------------
extern "C" void kernel_launch(void* const* d_in, const int* in_sizes, int n_in,
                              void* d_out, int out_size, void* d_ws, size_t ws_size,
                              hipStream_t stream) {
    const float* x     = (const float*)d_in[0];
    const float* ln1_g = (const float*)d_in[1];
    const float* ln1_b = (const float*)d_in[2];
    const float* qkv_w = (const float*)d_in[3];
    const float* qkv_b = (const float*)d_in[4];
    const float* out_w = (const float*)d_in[5];
    const float* out_b = (const float*)d_in[6];
    const float* ln2_g = (const float*)d_in[7];
    const float* ln2_b = (const float*)d_in[8];
    const float* fc1_w = (const float*)d_in[9];
    const float* fc1_b = (const float*)d_in[10];
    const float* fc2_w = (const float*)d_in[11];
    const float* fc2_b = (const float*)d_in[12];
    float* out = (float*)d_out;

    float* wsA = (float*)d_ws;                       // 96 MB = 25165824 floats
    float* wsB = wsA + (size_t)96 * 1024 * 1024 / 4; // 32 MB

    dim3 blk(256);

    // 1. h = LN1(x)            -> wsB
    ln_kernel<<<BT_, blk, 0, stream>>>(x, ln1_g, ln1_b, wsB);
    // 2. qkv = h @ qkv_w^T + b -> wsA   [8192,3072]
    gemm_nt<0, false><<<dim3(24, 64), blk, 0, stream>>>(wsB, qkv_w, qkv_b, nullptr,
                                                        wsA, BT_, 3 * C_, C_);
    // 3. o = attention(qkv)    -> wsB (h is dead)
    attn_kernel<<<dim3(8, 64), blk, 0, stream>>>(wsA, wsB);
    // 4. x1 = x + o @ out_w^T + b -> d_out
    gemm_nt<0, true><<<dim3(8, 64), blk, 0, stream>>>(wsB, out_w, out_b, x,
                                                      out, BT_, C_, C_);
    // 5. h2 = LN2(x1)          -> wsA[0:8M)
    ln_kernel<<<BT_, blk, 0, stream>>>(out, ln2_g, ln2_b, wsA);
    // 6. MLP in 2 chunks of 4096 rows (ff chunk reuses wsA+32MB, 64 MB)
    float* ff = wsA + (size_t)8 * 1024 * 1024;
    for (int c = 0; c < 2; ++c) {
        float* h2c = wsA + (size_t)c * 4096 * C_;
        float* oc  = out + (size_t)c * 4096 * C_;
        gemm_nt<1, false><<<dim3(32, 32), blk, 0, stream>>>(h2c, fc1_w, fc1_b, nullptr,
                                                            ff, 4096, FF_, C_);
        gemm_nt<0, true><<<dim3(8, 32), blk, 0, stream>>>(ff, fc2_w, fc2_b, oc,
                                                          oc, 4096, C_, FF_);
    }
}

// Round 3
// 3987.123 us; speedup vs baseline: 1.0947x; 1.0947x over previous
//
#include <hip/hip_runtime.h>
#include <cmath>

#define B_ 4
#define T_ 2048
#define C_ 1024
#define H_ 16
#define D_ 64
#define FF_ 4096
#define BT_ (B_ * T_)

// ---------------------------------------------------------------------------
// LayerNorm: one block per row (1024 floats), 256 threads, float4 loads.
// ---------------------------------------------------------------------------
__global__ __launch_bounds__(256) void ln_kernel(const float* __restrict__ x,
                                                 const float* __restrict__ g,
                                                 const float* __restrict__ b,
                                                 float* __restrict__ y) {
    __shared__ float ls[4], lq[4];
    __shared__ float mean_s, rstd_s;
    int row = blockIdx.x;
    const float4* xr = (const float4*)(x + (size_t)row * C_);
    float4 v = xr[threadIdx.x];
    float s = v.x + v.y + v.z + v.w;
    float sq = v.x * v.x + v.y * v.y + v.z * v.z + v.w * v.w;
#pragma unroll
    for (int off = 32; off > 0; off >>= 1) {
        s += __shfl_down(s, off);
        sq += __shfl_down(sq, off);
    }
    int wid = threadIdx.x >> 6, lane = threadIdx.x & 63;
    if (lane == 0) { ls[wid] = s; lq[wid] = sq; }
    __syncthreads();
    if (threadIdx.x == 0) {
        float S = ls[0] + ls[1] + ls[2] + ls[3];
        float Q = lq[0] + lq[1] + lq[2] + lq[3];
        float mean = S * (1.0f / C_);
        float var = Q * (1.0f / C_) - mean * mean;
        mean_s = mean;
        rstd_s = 1.0f / sqrtf(var + 1e-5f);
    }
    __syncthreads();
    float mean = mean_s, rstd = rstd_s;
    float4 gv = ((const float4*)g)[threadIdx.x];
    float4 bv = ((const float4*)b)[threadIdx.x];
    float4 o;
    o.x = (v.x - mean) * rstd * gv.x + bv.x;
    o.y = (v.y - mean) * rstd * gv.y + bv.y;
    o.z = (v.z - mean) * rstd * gv.z + bv.z;
    o.w = (v.w - mean) * rstd * gv.w + bv.w;
    ((float4*)(y + (size_t)row * C_))[threadIdx.x] = o;
}

// ---------------------------------------------------------------------------
// fp32 GEMM: C[M,N] = A[M,K] * W[N,K]^T (+bias, +gelu, +residual)
// 128x128x16 tiles, 256 threads, 8x8 outputs/thread. (unchanged this round)
// ---------------------------------------------------------------------------
template <int ACT, bool RES>
__global__ __launch_bounds__(256) void gemm_nt(const float* __restrict__ A,
                                               const float* __restrict__ W,
                                               const float* __restrict__ bias,
                                               const float* __restrict__ res,
                                               float* __restrict__ Cmat,
                                               int M, int N, int K) {
    __shared__ float As[16][128];
    __shared__ float Bs[16][128];
    int tid = threadIdx.x;
    int m0 = blockIdx.y * 128;
    int n0 = blockIdx.x * 128;
    int ty = tid >> 4, tx = tid & 15;
    int row = tid >> 2;       // 0..63
    int kq = (tid & 3) * 4;   // 0,4,8,12

    float acc[8][8];
#pragma unroll
    for (int i = 0; i < 8; ++i)
#pragma unroll
        for (int j = 0; j < 8; ++j) acc[i][j] = 0.0f;

    for (int k0 = 0; k0 < K; k0 += 16) {
        float4 a0 = *(const float4*)(A + (size_t)(m0 + row) * K + k0 + kq);
        float4 a1 = *(const float4*)(A + (size_t)(m0 + row + 64) * K + k0 + kq);
        float4 b0 = *(const float4*)(W + (size_t)(n0 + row) * K + k0 + kq);
        float4 b1 = *(const float4*)(W + (size_t)(n0 + row + 64) * K + k0 + kq);
        __syncthreads();  // previous tile fully consumed
        As[kq + 0][row] = a0.x; As[kq + 1][row] = a0.y;
        As[kq + 2][row] = a0.z; As[kq + 3][row] = a0.w;
        As[kq + 0][row + 64] = a1.x; As[kq + 1][row + 64] = a1.y;
        As[kq + 2][row + 64] = a1.z; As[kq + 3][row + 64] = a1.w;
        Bs[kq + 0][row] = b0.x; Bs[kq + 1][row] = b0.y;
        Bs[kq + 2][row] = b0.z; Bs[kq + 3][row] = b0.w;
        Bs[kq + 0][row + 64] = b1.x; Bs[kq + 1][row + 64] = b1.y;
        Bs[kq + 2][row + 64] = b1.z; Bs[kq + 3][row + 64] = b1.w;
        __syncthreads();
#pragma unroll
        for (int k = 0; k < 16; ++k) {
            float a[8], bb[8];
            *(float4*)&a[0] = *(const float4*)&As[k][ty * 4];
            *(float4*)&a[4] = *(const float4*)&As[k][64 + ty * 4];
            *(float4*)&bb[0] = *(const float4*)&Bs[k][tx * 4];
            *(float4*)&bb[4] = *(const float4*)&Bs[k][64 + tx * 4];
#pragma unroll
            for (int i = 0; i < 8; ++i)
#pragma unroll
                for (int j = 0; j < 8; ++j) acc[i][j] += a[i] * bb[j];
        }
    }

#pragma unroll
    for (int ia = 0; ia < 8; ++ia) {
        int mr = m0 + ((ia < 4) ? (ty * 4 + ia) : (64 + ty * 4 + (ia - 4)));
#pragma unroll
        for (int jh = 0; jh < 2; ++jh) {
            int nc = n0 + jh * 64 + tx * 4;
            float4 v;
            float* vp = &v.x;
#pragma unroll
            for (int jj = 0; jj < 4; ++jj) {
                float cv = acc[ia][jh * 4 + jj] + bias[nc + jj];
                if (ACT == 1) cv = 0.5f * cv * (1.0f + erff(cv * 0.70710678118654752f));
                if (RES) cv += res[(size_t)mr * N + nc + jj];
                vp[jj] = cv;
            }
            *(float4*)(Cmat + (size_t)mr * N + nc) = v;
        }
    }
}

// ---------------------------------------------------------------------------
// Flash attention fp32, v2.
// Block = 256 threads = 64 query-groups x 4 lanes; each thread serves TWO
// queries (rows qbase+ql and qbase+64+ql) and owns 16 of 64 d-elements.
// Per-thread state: q[2][16] + acc[2][16] + (m,l)x2  -> ~100 VGPR, no spill.
// Dot products complete via 2x __shfl_xor within the 4-lane group (branch
// stays uniform inside a group). K/V tiles (64x64) staged in LDS.
// ---------------------------------------------------------------------------
__device__ __forceinline__ void online_upd(float& m, float& l, float* acc, float s,
                                           float4 v0, float4 v1, float4 v2, float4 v3) {
    if (s <= m) {
        float p = __expf(s - m);
        l += p;
        acc[0]  = fmaf(p, v0.x, acc[0]);  acc[1]  = fmaf(p, v0.y, acc[1]);
        acc[2]  = fmaf(p, v0.z, acc[2]);  acc[3]  = fmaf(p, v0.w, acc[3]);
        acc[4]  = fmaf(p, v1.x, acc[4]);  acc[5]  = fmaf(p, v1.y, acc[5]);
        acc[6]  = fmaf(p, v1.z, acc[6]);  acc[7]  = fmaf(p, v1.w, acc[7]);
        acc[8]  = fmaf(p, v2.x, acc[8]);  acc[9]  = fmaf(p, v2.y, acc[9]);
        acc[10] = fmaf(p, v2.z, acc[10]); acc[11] = fmaf(p, v2.w, acc[11]);
        acc[12] = fmaf(p, v3.x, acc[12]); acc[13] = fmaf(p, v3.y, acc[13]);
        acc[14] = fmaf(p, v3.z, acc[14]); acc[15] = fmaf(p, v3.w, acc[15]);
    } else {
        float sc = __expf(m - s);
        m = s;
        l = fmaf(l, sc, 1.0f);
        acc[0]  = fmaf(acc[0],  sc, v0.x); acc[1]  = fmaf(acc[1],  sc, v0.y);
        acc[2]  = fmaf(acc[2],  sc, v0.z); acc[3]  = fmaf(acc[3],  sc, v0.w);
        acc[4]  = fmaf(acc[4],  sc, v1.x); acc[5]  = fmaf(acc[5],  sc, v1.y);
        acc[6]  = fmaf(acc[6],  sc, v1.z); acc[7]  = fmaf(acc[7],  sc, v1.w);
        acc[8]  = fmaf(acc[8],  sc, v2.x); acc[9]  = fmaf(acc[9],  sc, v2.y);
        acc[10] = fmaf(acc[10], sc, v2.z); acc[11] = fmaf(acc[11], sc, v2.w);
        acc[12] = fmaf(acc[12], sc, v3.x); acc[13] = fmaf(acc[13], sc, v3.y);
        acc[14] = fmaf(acc[14], sc, v3.z); acc[15] = fmaf(acc[15], sc, v3.w);
    }
}

__global__ __launch_bounds__(256) void attn_kernel(const float* __restrict__ qkv,
                                                   float* __restrict__ o) {
    __shared__ float Ks[64][64];
    __shared__ float Vs[64][64];
    int bh = blockIdx.y;
    int bb = bh >> 4;
    int h = bh & 15;
    int ql = threadIdx.x >> 2;   // 0..63 query-group
    int dg = threadIdx.x & 3;    // 0..3 d-quarter
    int qbase = blockIdx.x * 128;
    int q0 = qbase + ql;
    int q1 = qbase + 64 + ql;

    float qA[16], qB[16], acc0[16], acc1[16];
    const float* qr0 = qkv + (size_t)(bb * T_ + q0) * 3072 + h * 64 + dg * 16;
    const float* qr1 = qkv + (size_t)(bb * T_ + q1) * 3072 + h * 64 + dg * 16;
#pragma unroll
    for (int i = 0; i < 4; ++i) {
        float4 v0 = *(const float4*)(qr0 + i * 4);
        float4 v1 = *(const float4*)(qr1 + i * 4);
        qA[i * 4 + 0] = v0.x * 0.125f; qA[i * 4 + 1] = v0.y * 0.125f;
        qA[i * 4 + 2] = v0.z * 0.125f; qA[i * 4 + 3] = v0.w * 0.125f;
        qB[i * 4 + 0] = v1.x * 0.125f; qB[i * 4 + 1] = v1.y * 0.125f;
        qB[i * 4 + 2] = v1.z * 0.125f; qB[i * 4 + 3] = v1.w * 0.125f;
        acc0[i * 4 + 0] = 0.f; acc0[i * 4 + 1] = 0.f; acc0[i * 4 + 2] = 0.f; acc0[i * 4 + 3] = 0.f;
        acc1[i * 4 + 0] = 0.f; acc1[i * 4 + 1] = 0.f; acc1[i * 4 + 2] = 0.f; acc1[i * 4 + 3] = 0.f;
    }
    float m0 = -INFINITY, l0 = 0.f, m1 = -INFINITY, l1 = 0.f;

    int ntiles = blockIdx.x * 2 + 2;
    for (int tile = 0; tile < ntiles; ++tile) {
        int kt0 = tile << 6;
        __syncthreads();  // previous tile consumed
#pragma unroll
        for (int i = 0; i < 4; ++i) {
            int f4 = threadIdx.x + i * 256;
            int j = f4 >> 4;
            int d4 = (f4 & 15) * 4;
            const float* kp = qkv + (size_t)(bb * T_ + kt0 + j) * 3072 + 1024 + h * 64 + d4;
            *(float4*)&Ks[j][d4] = *(const float4*)kp;
            *(float4*)&Vs[j][d4] = *(const float4*)(kp + 1024);
        }
        __syncthreads();
        int je0 = q0 - kt0; if (je0 > 63) je0 = 63;   // may be <0 on last tile
        int je1 = q1 - kt0; if (je1 > 63) je1 = 63;   // always >= 0, >= je0
        for (int j = 0; j <= je1; ++j) {
            const float4* kr = (const float4*)&Ks[j][dg * 16];
            float4 k0 = kr[0], k1 = kr[1], k2 = kr[2], k3 = kr[3];
            float s0, s1;
            s0 = qA[0] * k0.x;             s1 = qB[0] * k0.x;
            s0 = fmaf(qA[1], k0.y, s0);    s1 = fmaf(qB[1], k0.y, s1);
            s0 = fmaf(qA[2], k0.z, s0);    s1 = fmaf(qB[2], k0.z, s1);
            s0 = fmaf(qA[3], k0.w, s0);    s1 = fmaf(qB[3], k0.w, s1);
            s0 = fmaf(qA[4], k1.x, s0);    s1 = fmaf(qB[4], k1.x, s1);
            s0 = fmaf(qA[5], k1.y, s0);    s1 = fmaf(qB[5], k1.y, s1);
            s0 = fmaf(qA[6], k1.z, s0);    s1 = fmaf(qB[6], k1.z, s1);
            s0 = fmaf(qA[7], k1.w, s0);    s1 = fmaf(qB[7], k1.w, s1);
            s0 = fmaf(qA[8], k2.x, s0);    s1 = fmaf(qB[8], k2.x, s1);
            s0 = fmaf(qA[9], k2.y, s0);    s1 = fmaf(qB[9], k2.y, s1);
            s0 = fmaf(qA[10], k2.z, s0);   s1 = fmaf(qB[10], k2.z, s1);
            s0 = fmaf(qA[11], k2.w, s0);   s1 = fmaf(qB[11], k2.w, s1);
            s0 = fmaf(qA[12], k3.x, s0);   s1 = fmaf(qB[12], k3.x, s1);
            s0 = fmaf(qA[13], k3.y, s0);   s1 = fmaf(qB[13], k3.y, s1);
            s0 = fmaf(qA[14], k3.z, s0);   s1 = fmaf(qB[14], k3.z, s1);
            s0 = fmaf(qA[15], k3.w, s0);   s1 = fmaf(qB[15], k3.w, s1);
            // close the dot across the 4-lane group
            s0 += __shfl_xor(s0, 1); s0 += __shfl_xor(s0, 2);
            s1 += __shfl_xor(s1, 1); s1 += __shfl_xor(s1, 2);
            const float4* vr = (const float4*)&Vs[j][dg * 16];
            float4 v0 = vr[0], v1 = vr[1], v2 = vr[2], v3 = vr[3];
            if (j <= je0) online_upd(m0, l0, acc0, s0, v0, v1, v2, v3);
            online_upd(m1, l1, acc1, s1, v0, v1, v2, v3);
        }
    }
    float inv0 = 1.0f / l0;
    float inv1 = 1.0f / l1;
    float* or0 = o + (size_t)(bb * T_ + q0) * 1024 + h * 64 + dg * 16;
    float* or1 = o + (size_t)(bb * T_ + q1) * 1024 + h * 64 + dg * 16;
#pragma unroll
    for (int i = 0; i < 4; ++i) {
        float4 w0, w1;
        w0.x = acc0[i * 4 + 0] * inv0; w0.y = acc0[i * 4 + 1] * inv0;
        w0.z = acc0[i * 4 + 2] * inv0; w0.w = acc0[i * 4 + 3] * inv0;
        w1.x = acc1[i * 4 + 0] * inv1; w1.y = acc1[i * 4 + 1] * inv1;
        w1.z = acc1[i * 4 + 2] * inv1; w1.w = acc1[i * 4 + 3] * inv1;
        *(float4*)(or0 + i * 4) = w0;
        *(float4*)(or1 + i * 4) = w1;
    }
}

// ---------------------------------------------------------------------------
// Orchestration. Workspace layout (needs 128 MB):
//   wsA = ws+0      : 96 MB. Phase 1: qkv [8192,3072].
//                     Phase 2: h2 [8192,1024] (32MB) + ff chunk [4096,4096] (64MB)
//   wsB = ws+96MB   : 32 MB. Phase 1: ln1 out h [8192,1024]; then attn out o.
//   x1 (post-attn residual) lives in d_out; fc2 adds into it in place.
// ---------------------------------------------------------------------------
extern "C" void kernel_launch(void* const* d_in, const int* in_sizes, int n_in,
                              void* d_out, int out_size, void* d_ws, size_t ws_size,
                              hipStream_t stream) {
    const float* x     = (const float*)d_in[0];
    const float* ln1_g = (const float*)d_in[1];
    const float* ln1_b = (const float*)d_in[2];
    const float* qkv_w = (const float*)d_in[3];
    const float* qkv_b = (const float*)d_in[4];
    const float* out_w = (const float*)d_in[5];
    const float* out_b = (const float*)d_in[6];
    const float* ln2_g = (const float*)d_in[7];
    const float* ln2_b = (const float*)d_in[8];
    const float* fc1_w = (const float*)d_in[9];
    const float* fc1_b = (const float*)d_in[10];
    const float* fc2_w = (const float*)d_in[11];
    const float* fc2_b = (const float*)d_in[12];
    float* out = (float*)d_out;

    float* wsA = (float*)d_ws;                       // 96 MB = 25165824 floats
    float* wsB = wsA + (size_t)96 * 1024 * 1024 / 4; // 32 MB

    dim3 blk(256);

    // 1. h = LN1(x)            -> wsB
    ln_kernel<<<BT_, blk, 0, stream>>>(x, ln1_g, ln1_b, wsB);
    // 2. qkv = h @ qkv_w^T + b -> wsA   [8192,3072]
    gemm_nt<0, false><<<dim3(24, 64), blk, 0, stream>>>(wsB, qkv_w, qkv_b, nullptr,
                                                        wsA, BT_, 3 * C_, C_);
    // 3. o = attention(qkv)    -> wsB (h is dead)
    attn_kernel<<<dim3(16, 64), blk, 0, stream>>>(wsA, wsB);
    // 4. x1 = x + o @ out_w^T + b -> d_out
    gemm_nt<0, true><<<dim3(8, 64), blk, 0, stream>>>(wsB, out_w, out_b, x,
                                                      out, BT_, C_, C_);
    // 5. h2 = LN2(x1)          -> wsA[0:8M)
    ln_kernel<<<BT_, blk, 0, stream>>>(out, ln2_g, ln2_b, wsA);
    // 6. MLP in 2 chunks of 4096 rows (ff chunk reuses wsA+32MB, 64 MB)
    float* ff = wsA + (size_t)8 * 1024 * 1024;
    for (int c = 0; c < 2; ++c) {
        float* h2c = wsA + (size_t)c * 4096 * C_;
        float* oc  = out + (size_t)c * 4096 * C_;
        gemm_nt<1, false><<<dim3(32, 32), blk, 0, stream>>>(h2c, fc1_w, fc1_b, nullptr,
                                                            ff, 4096, FF_, C_);
        gemm_nt<0, true><<<dim3(8, 32), blk, 0, stream>>>(ff, fc2_w, fc2_b, oc,
                                                          oc, 4096, C_, FF_);
    }
}

// Round 4
// 1551.083 us; speedup vs baseline: 2.8140x; 2.5705x over previous
//
#include <hip/hip_runtime.h>
#include <cmath>

#define B_ 4
#define T_ 2048
#define C_ 1024
#define H_ 16
#define D_ 64
#define FF_ 4096
#define BT_ (B_ * T_)

typedef __attribute__((ext_vector_type(8))) short bf16x8;   // 8 bf16 = 4 VGPRs
typedef __attribute__((ext_vector_type(4))) float f32x4;

// fp32 -> bf16 round-to-nearest-even (bit ops; no hip_bf16.h dependency)
__device__ __forceinline__ unsigned short f2bf(float f) {
    union { float f; unsigned int u; } c; c.f = f;
    unsigned int u = c.u + 0x7FFFu + ((c.u >> 16) & 1u);
    return (unsigned short)(u >> 16);
}
__device__ __forceinline__ float bf2f(unsigned short u) {
    union { unsigned int u; float f; } c; c.u = ((unsigned int)u) << 16;
    return c.f;
}

// async global->LDS, 16B per lane. LDS dest is wave-uniform base + lane*16.
__device__ __forceinline__ void gload_lds16(const unsigned short* g, unsigned short* l) {
    __builtin_amdgcn_global_load_lds((const __attribute__((address_space(1))) void*)g,
                                     (__attribute__((address_space(3))) void*)l, 16, 0, 0);
}

// ---------------------------------------------------------------------------
// fp32 -> bf16 convert (weights), grid-stride, float4 in / ushort4 out.
// ---------------------------------------------------------------------------
__global__ __launch_bounds__(256) void cvt_kernel(const float* __restrict__ src,
                                                  unsigned short* __restrict__ dst, int n4) {
    int i = blockIdx.x * 256 + threadIdx.x;
    int stride = gridDim.x * 256;
    for (; i < n4; i += stride) {
        float4 v = ((const float4*)src)[i];
        ushort4 o;
        o.x = f2bf(v.x); o.y = f2bf(v.y); o.z = f2bf(v.z); o.w = f2bf(v.w);
        ((ushort4*)dst)[i] = o;
    }
}

// ---------------------------------------------------------------------------
// LayerNorm: one block per row (1024 floats), 256 threads; bf16 output.
// ---------------------------------------------------------------------------
__global__ __launch_bounds__(256) void ln_kernel(const float* __restrict__ x,
                                                 const float* __restrict__ g,
                                                 const float* __restrict__ b,
                                                 unsigned short* __restrict__ y) {
    __shared__ float ls[4], lq[4];
    __shared__ float mean_s, rstd_s;
    int row = blockIdx.x;
    const float4* xr = (const float4*)(x + (size_t)row * C_);
    float4 v = xr[threadIdx.x];
    float s = v.x + v.y + v.z + v.w;
    float sq = v.x * v.x + v.y * v.y + v.z * v.z + v.w * v.w;
#pragma unroll
    for (int off = 32; off > 0; off >>= 1) {
        s += __shfl_down(s, off);
        sq += __shfl_down(sq, off);
    }
    int wid = threadIdx.x >> 6, lane = threadIdx.x & 63;
    if (lane == 0) { ls[wid] = s; lq[wid] = sq; }
    __syncthreads();
    if (threadIdx.x == 0) {
        float S = ls[0] + ls[1] + ls[2] + ls[3];
        float Q = lq[0] + lq[1] + lq[2] + lq[3];
        float mean = S * (1.0f / C_);
        float var = Q * (1.0f / C_) - mean * mean;
        mean_s = mean;
        rstd_s = 1.0f / sqrtf(var + 1e-5f);
    }
    __syncthreads();
    float mean = mean_s, rstd = rstd_s;
    float4 gv = ((const float4*)g)[threadIdx.x];
    float4 bv = ((const float4*)b)[threadIdx.x];
    ushort4 o;
    o.x = f2bf((v.x - mean) * rstd * gv.x + bv.x);
    o.y = f2bf((v.y - mean) * rstd * gv.y + bv.y);
    o.z = f2bf((v.z - mean) * rstd * gv.z + bv.z);
    o.w = f2bf((v.w - mean) * rstd * gv.w + bv.w);
    ((ushort4*)(y + (size_t)row * C_))[threadIdx.x] = o;
}

// ---------------------------------------------------------------------------
// bf16 MFMA GEMM (m97 structure): C[M,N] = A[M,K] @ W[N,K]^T (+bias/gelu/res)
// 128x128 tile, BK=32, 256 threads = 4 waves (2x2), each wave 64x64 out via
// 4x4 frags of 16x16x32 MFMA, fp32 accum. A,W bf16; bias/res fp32.
// OBF=1: write bf16 to Cb; OBF=0: write fp32 to Cf.
// ---------------------------------------------------------------------------
template <int ACT, int RES, int OBF>
__global__ __launch_bounds__(256, 2) void gemm_mfma(
        const unsigned short* __restrict__ A,
        const unsigned short* __restrict__ W,
        const float* __restrict__ bias,
        const float* __restrict__ res,
        float* __restrict__ Cf,
        unsigned short* __restrict__ Cb,
        int M, int N, int K) {
    __shared__ unsigned short As[128 * 32];
    __shared__ unsigned short Bs[128 * 32];
    int tid = threadIdx.x;
    int lane = tid & 63, wid = tid >> 6;
    int wr = wid >> 1, wc = wid & 1;
    int m0 = blockIdx.y * 128, n0 = blockIdx.x * 128;

    // staging: chunk = tid + issue*256; row = chunk>>2 (0..127), kslot = (tid&3)*8
    const unsigned short* Ag = A + (size_t)(m0 + (tid >> 2)) * K + (tid & 3) * 8;
    const unsigned short* Wg = W + (size_t)(n0 + (tid >> 2)) * K + (tid & 3) * 8;
    unsigned short* Al0 = As + (size_t)(wid * 64) * 8;          // wave-uniform bases
    unsigned short* Al1 = As + (size_t)(256 + wid * 64) * 8;
    unsigned short* Bl0 = Bs + (size_t)(wid * 64) * 8;
    unsigned short* Bl1 = Bs + (size_t)(256 + wid * 64) * 8;

    f32x4 acc[4][4] = {};

    // fragment read: lane holds row (lane&15), k = (lane>>4)*8 + [0..7]
    int ar = lane & 15, ac8 = (lane >> 4) * 8;
    int aoffA = (wr * 64 + ar) * 32 + ac8;
    int aoffB = (wc * 64 + ar) * 32 + ac8;

    for (int k0 = 0; k0 < K; k0 += 32) {
        __syncthreads();                       // all waves done reading prev tile
        gload_lds16(Ag, Al0);
        gload_lds16(Ag + (size_t)64 * K, Al1);
        gload_lds16(Wg, Bl0);
        gload_lds16(Wg + (size_t)64 * K, Bl1);
        Ag += 32; Wg += 32;
        __syncthreads();                       // compiler drains vmcnt before barrier
        bf16x8 af[4], bw[4];
#pragma unroll
        for (int i = 0; i < 4; ++i) {
            af[i] = *(const bf16x8*)&As[aoffA + i * 16 * 32];
            bw[i] = *(const bf16x8*)&Bs[aoffB + i * 16 * 32];
        }
#pragma unroll
        for (int mi = 0; mi < 4; ++mi)
#pragma unroll
            for (int ni = 0; ni < 4; ++ni)
                acc[mi][ni] = __builtin_amdgcn_mfma_f32_16x16x32_bf16(
                    af[mi], bw[ni], acc[mi][ni], 0, 0, 0);
    }

    // C/D layout (m89-verified): col = lane&15, row = (lane>>4)*4 + j
    int cr = (lane >> 4) * 4;
    int cc = lane & 15;
#pragma unroll
    for (int mi = 0; mi < 4; ++mi) {
#pragma unroll
        for (int ni = 0; ni < 4; ++ni) {
            int col = n0 + wc * 64 + ni * 16 + cc;
            float bsv = bias[col];
#pragma unroll
            for (int j = 0; j < 4; ++j) {
                int row = m0 + wr * 64 + mi * 16 + cr + j;
                float v = acc[mi][ni][j] + bsv;
                if (ACT) v = 0.5f * v * (1.0f + erff(v * 0.70710678118654752f));
                if (RES) v += res[(size_t)row * N + col];
                if (OBF) Cb[(size_t)row * N + col] = f2bf(v);
                else     Cf[(size_t)row * N + col] = v;
            }
        }
    }
}

// ---------------------------------------------------------------------------
// Flash attention fp32 math, bf16 I/O. 256 threads = 64 query-groups x 4
// lanes; 2 queries/thread, 16 of 64 d-elems each. launch_bounds(256,2) so the
// backend stops capping VGPRs at 64 (round-3 spill).
// ---------------------------------------------------------------------------
__device__ __forceinline__ void online_upd(float& m, float& l, float* acc, float s,
                                           const float* v) {
    if (s <= m) {
        float p = __expf(s - m);
        l += p;
#pragma unroll
        for (int e = 0; e < 16; ++e) acc[e] = fmaf(p, v[e], acc[e]);
    } else {
        float sc = __expf(m - s);
        m = s;
        l = fmaf(l, sc, 1.0f);
#pragma unroll
        for (int e = 0; e < 16; ++e) acc[e] = fmaf(acc[e], sc, v[e]);
    }
}

__global__ __launch_bounds__(256, 2) void attn_kernel(const unsigned short* __restrict__ qkv,
                                                      unsigned short* __restrict__ o) {
    __shared__ float Ks[64][64];
    __shared__ float Vs[64][64];
    int bh = blockIdx.y;
    int bb = bh >> 4;
    int h = bh & 15;
    int ql = threadIdx.x >> 2;
    int dg = threadIdx.x & 3;
    int qbase = blockIdx.x * 128;
    int q0 = qbase + ql;
    int q1 = qbase + 64 + ql;

    float qA[16], qB[16], acc0[16], acc1[16];
    const unsigned short* qr0 = qkv + (size_t)(bb * T_ + q0) * 3072 + h * 64 + dg * 16;
    const unsigned short* qr1 = qkv + (size_t)(bb * T_ + q1) * 3072 + h * 64 + dg * 16;
    {
        bf16x8 a0 = *(const bf16x8*)qr0, a1 = *(const bf16x8*)(qr0 + 8);
        bf16x8 b0 = *(const bf16x8*)qr1, b1 = *(const bf16x8*)(qr1 + 8);
#pragma unroll
        for (int e = 0; e < 8; ++e) {
            qA[e]     = bf2f((unsigned short)a0[e]) * 0.125f;
            qA[e + 8] = bf2f((unsigned short)a1[e]) * 0.125f;
            qB[e]     = bf2f((unsigned short)b0[e]) * 0.125f;
            qB[e + 8] = bf2f((unsigned short)b1[e]) * 0.125f;
        }
    }
#pragma unroll
    for (int e = 0; e < 16; ++e) { acc0[e] = 0.f; acc1[e] = 0.f; }
    float m0 = -INFINITY, l0 = 0.f, m1 = -INFINITY, l1 = 0.f;

    int ntiles = blockIdx.x * 2 + 2;
    for (int tile = 0; tile < ntiles; ++tile) {
        int kt0 = tile << 6;
        __syncthreads();
#pragma unroll
        for (int i = 0; i < 2; ++i) {
            int chunk = threadIdx.x + i * 256;   // 512 chunks of 8 bf16
            int j = chunk >> 3, d8 = (chunk & 7) * 8;
            const unsigned short* kp =
                qkv + (size_t)(bb * T_ + kt0 + j) * 3072 + 1024 + h * 64 + d8;
            bf16x8 kv = *(const bf16x8*)kp;
            bf16x8 vv = *(const bf16x8*)(kp + 1024);
#pragma unroll
            for (int e = 0; e < 8; ++e) {
                Ks[j][d8 + e] = bf2f((unsigned short)kv[e]);
                Vs[j][d8 + e] = bf2f((unsigned short)vv[e]);
            }
        }
        __syncthreads();
        int je0 = q0 - kt0; if (je0 > 63) je0 = 63;
        int je1 = q1 - kt0; if (je1 > 63) je1 = 63;
        for (int j = 0; j <= je1; ++j) {
            const float* kr = &Ks[j][dg * 16];
            float s0 = 0.f, s1 = 0.f;
#pragma unroll
            for (int e = 0; e < 16; ++e) {
                s0 = fmaf(qA[e], kr[e], s0);
                s1 = fmaf(qB[e], kr[e], s1);
            }
            s0 += __shfl_xor(s0, 1); s0 += __shfl_xor(s0, 2);
            s1 += __shfl_xor(s1, 1); s1 += __shfl_xor(s1, 2);
            float vfrag[16];
            const float* vr = &Vs[j][dg * 16];
#pragma unroll
            for (int e = 0; e < 16; ++e) vfrag[e] = vr[e];
            if (j <= je0) online_upd(m0, l0, acc0, s0, vfrag);
            online_upd(m1, l1, acc1, s1, vfrag);
        }
    }
    float inv0 = 1.0f / l0;
    float inv1 = 1.0f / l1;
    unsigned short* or0 = o + (size_t)(bb * T_ + q0) * 1024 + h * 64 + dg * 16;
    unsigned short* or1 = o + (size_t)(bb * T_ + q1) * 1024 + h * 64 + dg * 16;
#pragma unroll
    for (int i = 0; i < 4; ++i) {
        ushort4 w0, w1;
        w0.x = f2bf(acc0[i * 4 + 0] * inv0); w0.y = f2bf(acc0[i * 4 + 1] * inv0);
        w0.z = f2bf(acc0[i * 4 + 2] * inv0); w0.w = f2bf(acc0[i * 4 + 3] * inv0);
        w1.x = f2bf(acc1[i * 4 + 0] * inv1); w1.y = f2bf(acc1[i * 4 + 1] * inv1);
        w1.z = f2bf(acc1[i * 4 + 2] * inv1); w1.w = f2bf(acc1[i * 4 + 3] * inv1);
        *(ushort4*)(or0 + i * 4) = w0;
        *(ushort4*)(or1 + i * 4) = w1;
    }
}

// ---------------------------------------------------------------------------
// Workspace layout (104 MB peak, all bf16 intermediates):
//   [0,6)    wq bf16      [6,8)  wo bf16    [8,16) wf1 bf16   [16,24) wf2 bf16
//   [24,72)  qkv bf16 [8192,3072]     (phase 2: [24,40) ln2 bf16, [40,104) ff bf16)
//   [72,88)  h bf16 (ln1 out), then attn out o bf16 (h dead by then)
//   x1 fp32 lives in d_out; fc2 accumulates into it in place.
// ---------------------------------------------------------------------------
extern "C" void kernel_launch(void* const* d_in, const int* in_sizes, int n_in,
                              void* d_out, int out_size, void* d_ws, size_t ws_size,
                              hipStream_t stream) {
    const float* x     = (const float*)d_in[0];
    const float* ln1_g = (const float*)d_in[1];
    const float* ln1_b = (const float*)d_in[2];
    const float* qkv_w = (const float*)d_in[3];
    const float* qkv_b = (const float*)d_in[4];
    const float* out_w = (const float*)d_in[5];
    const float* out_b = (const float*)d_in[6];
    const float* ln2_g = (const float*)d_in[7];
    const float* ln2_b = (const float*)d_in[8];
    const float* fc1_w = (const float*)d_in[9];
    const float* fc1_b = (const float*)d_in[10];
    const float* fc2_w = (const float*)d_in[11];
    const float* fc2_b = (const float*)d_in[12];
    float* out = (float*)d_out;

    const size_t MB = 1024 * 1024;
    char* wsc = (char*)d_ws;
    unsigned short* wq   = (unsigned short*)(wsc);
    unsigned short* wo   = (unsigned short*)(wsc + 6 * MB);
    unsigned short* wf1  = (unsigned short*)(wsc + 8 * MB);
    unsigned short* wf2  = (unsigned short*)(wsc + 16 * MB);
    unsigned short* qkvb = (unsigned short*)(wsc + 24 * MB);
    unsigned short* hb   = (unsigned short*)(wsc + 72 * MB);   // h, later o
    unsigned short* ln2b = (unsigned short*)(wsc + 24 * MB);   // reuse qkv region
    unsigned short* ffb  = (unsigned short*)(wsc + 40 * MB);

    dim3 blk(256);

    // weight converts (fresh every call; ws is re-poisoned by the harness)
    cvt_kernel<<<1024, blk, 0, stream>>>(qkv_w, wq, 3 * C_ * C_ / 4);
    cvt_kernel<<<1024, blk, 0, stream>>>(out_w, wo, C_ * C_ / 4);
    cvt_kernel<<<1024, blk, 0, stream>>>(fc1_w, wf1, FF_ * C_ / 4);
    cvt_kernel<<<1024, blk, 0, stream>>>(fc2_w, wf2, FF_ * C_ / 4);

    // 1. h = LN1(x) -> bf16
    ln_kernel<<<BT_, blk, 0, stream>>>(x, ln1_g, ln1_b, hb);
    // 2. qkv = h @ qkv_w^T + b -> bf16 [8192,3072]
    gemm_mfma<0, 0, 1><<<dim3(24, 64), blk, 0, stream>>>(hb, wq, qkv_b, nullptr,
                                                         nullptr, qkvb, BT_, 3 * C_, C_);
    // 3. o = attention(qkv) -> bf16 (overwrites h; h dead)
    attn_kernel<<<dim3(16, 64), blk, 0, stream>>>(qkvb, hb);
    // 4. x1 = x + o @ out_w^T + b -> d_out fp32
    gemm_mfma<0, 1, 0><<<dim3(8, 64), blk, 0, stream>>>(hb, wo, out_b, x,
                                                        out, nullptr, BT_, C_, C_);
    // 5. h2 = LN2(x1) -> bf16 (into dead qkv region)
    ln_kernel<<<BT_, blk, 0, stream>>>(out, ln2_g, ln2_b, ln2b);
    // 6. ff = gelu(h2 @ fc1_w^T + b) -> bf16 [8192,4096]
    gemm_mfma<1, 0, 1><<<dim3(32, 64), blk, 0, stream>>>(ln2b, wf1, fc1_b, nullptr,
                                                         nullptr, ffb, BT_, FF_, C_);
    // 7. out = x1 + ff @ fc2_w^T + b (in place on d_out)
    gemm_mfma<0, 1, 0><<<dim3(8, 64), blk, 0, stream>>>(ffb, wf2, fc2_b, out,
                                                        out, nullptr, BT_, C_, FF_);
}

// Round 5
// 670.581 us; speedup vs baseline: 6.5090x; 2.3130x over previous
//
#include <hip/hip_runtime.h>
#include <cmath>

#define B_ 4
#define T_ 2048
#define C_ 1024
#define H_ 16
#define D_ 64
#define FF_ 4096
#define BT_ (B_ * T_)

typedef __attribute__((ext_vector_type(8))) short bf16x8;   // 8 bf16 = 4 VGPRs
typedef __attribute__((ext_vector_type(4))) float f32x4;

// fp32 -> bf16 round-to-nearest-even (bit ops; no hip_bf16.h dependency)
__device__ __forceinline__ unsigned short f2bf(float f) {
    union { float f; unsigned int u; } c; c.f = f;
    unsigned int u = c.u + 0x7FFFu + ((c.u >> 16) & 1u);
    return (unsigned short)(u >> 16);
}
__device__ __forceinline__ float bf2f(unsigned short u) {
    union { unsigned int u; float f; } c; c.u = ((unsigned int)u) << 16;
    return c.f;
}

// async global->LDS, 16B per lane. LDS dest is wave-uniform base + lane*16.
__device__ __forceinline__ void gload_lds16(const unsigned short* g, unsigned short* l) {
    __builtin_amdgcn_global_load_lds((const __attribute__((address_space(1))) void*)g,
                                     (__attribute__((address_space(3))) void*)l, 16, 0, 0);
}

// ---------------------------------------------------------------------------
// fp32 -> bf16 convert (weights), grid-stride, float4 in / ushort4 out.
// ---------------------------------------------------------------------------
__global__ __launch_bounds__(256) void cvt_kernel(const float* __restrict__ src,
                                                  unsigned short* __restrict__ dst, int n4) {
    int i = blockIdx.x * 256 + threadIdx.x;
    int stride = gridDim.x * 256;
    for (; i < n4; i += stride) {
        float4 v = ((const float4*)src)[i];
        ushort4 o;
        o.x = f2bf(v.x); o.y = f2bf(v.y); o.z = f2bf(v.z); o.w = f2bf(v.w);
        ((ushort4*)dst)[i] = o;
    }
}

// ---------------------------------------------------------------------------
// LayerNorm: one block per row (1024 floats), 256 threads; bf16 output.
// ---------------------------------------------------------------------------
__global__ __launch_bounds__(256) void ln_kernel(const float* __restrict__ x,
                                                 const float* __restrict__ g,
                                                 const float* __restrict__ b,
                                                 unsigned short* __restrict__ y) {
    __shared__ float ls[4], lq[4];
    __shared__ float mean_s, rstd_s;
    int row = blockIdx.x;
    const float4* xr = (const float4*)(x + (size_t)row * C_);
    float4 v = xr[threadIdx.x];
    float s = v.x + v.y + v.z + v.w;
    float sq = v.x * v.x + v.y * v.y + v.z * v.z + v.w * v.w;
#pragma unroll
    for (int off = 32; off > 0; off >>= 1) {
        s += __shfl_down(s, off);
        sq += __shfl_down(sq, off);
    }
    int wid = threadIdx.x >> 6, lane = threadIdx.x & 63;
    if (lane == 0) { ls[wid] = s; lq[wid] = sq; }
    __syncthreads();
    if (threadIdx.x == 0) {
        float S = ls[0] + ls[1] + ls[2] + ls[3];
        float Q = lq[0] + lq[1] + lq[2] + lq[3];
        float mean = S * (1.0f / C_);
        float var = Q * (1.0f / C_) - mean * mean;
        mean_s = mean;
        rstd_s = 1.0f / sqrtf(var + 1e-5f);
    }
    __syncthreads();
    float mean = mean_s, rstd = rstd_s;
    float4 gv = ((const float4*)g)[threadIdx.x];
    float4 bv = ((const float4*)b)[threadIdx.x];
    ushort4 o;
    o.x = f2bf((v.x - mean) * rstd * gv.x + bv.x);
    o.y = f2bf((v.y - mean) * rstd * gv.y + bv.y);
    o.z = f2bf((v.z - mean) * rstd * gv.z + bv.z);
    o.w = f2bf((v.w - mean) * rstd * gv.w + bv.w);
    ((ushort4*)(y + (size_t)row * C_))[threadIdx.x] = o;
}

// ---------------------------------------------------------------------------
// bf16 MFMA GEMM (m97 structure): C[M,N] = A[M,K] @ W[N,K]^T (+bias/gelu/res)
// 128x128 tile, BK=32, 256 threads = 4 waves (2x2), each wave 64x64 out via
// 4x4 frags of 16x16x32 MFMA, fp32 accum. A,W bf16; bias/res fp32.
// ---------------------------------------------------------------------------
template <int ACT, int RES, int OBF>
__global__ __launch_bounds__(256, 2) void gemm_mfma(
        const unsigned short* __restrict__ A,
        const unsigned short* __restrict__ W,
        const float* __restrict__ bias,
        const float* __restrict__ res,
        float* __restrict__ Cf,
        unsigned short* __restrict__ Cb,
        int M, int N, int K) {
    __shared__ unsigned short As[128 * 32];
    __shared__ unsigned short Bs[128 * 32];
    int tid = threadIdx.x;
    int lane = tid & 63, wid = tid >> 6;
    int wr = wid >> 1, wc = wid & 1;
    int m0 = blockIdx.y * 128, n0 = blockIdx.x * 128;

    const unsigned short* Ag = A + (size_t)(m0 + (tid >> 2)) * K + (tid & 3) * 8;
    const unsigned short* Wg = W + (size_t)(n0 + (tid >> 2)) * K + (tid & 3) * 8;
    unsigned short* Al0 = As + (size_t)(wid * 64) * 8;
    unsigned short* Al1 = As + (size_t)(256 + wid * 64) * 8;
    unsigned short* Bl0 = Bs + (size_t)(wid * 64) * 8;
    unsigned short* Bl1 = Bs + (size_t)(256 + wid * 64) * 8;

    f32x4 acc[4][4] = {};

    int ar = lane & 15, ac8 = (lane >> 4) * 8;
    int aoffA = (wr * 64 + ar) * 32 + ac8;
    int aoffB = (wc * 64 + ar) * 32 + ac8;

    for (int k0 = 0; k0 < K; k0 += 32) {
        __syncthreads();
        gload_lds16(Ag, Al0);
        gload_lds16(Ag + (size_t)64 * K, Al1);
        gload_lds16(Wg, Bl0);
        gload_lds16(Wg + (size_t)64 * K, Bl1);
        Ag += 32; Wg += 32;
        __syncthreads();
        bf16x8 af[4], bw[4];
#pragma unroll
        for (int i = 0; i < 4; ++i) {
            af[i] = *(const bf16x8*)&As[aoffA + i * 16 * 32];
            bw[i] = *(const bf16x8*)&Bs[aoffB + i * 16 * 32];
        }
#pragma unroll
        for (int mi = 0; mi < 4; ++mi)
#pragma unroll
            for (int ni = 0; ni < 4; ++ni)
                acc[mi][ni] = __builtin_amdgcn_mfma_f32_16x16x32_bf16(
                    af[mi], bw[ni], acc[mi][ni], 0, 0, 0);
    }

    int cr = (lane >> 4) * 4;
    int cc = lane & 15;
#pragma unroll
    for (int mi = 0; mi < 4; ++mi) {
#pragma unroll
        for (int ni = 0; ni < 4; ++ni) {
            int col = n0 + wc * 64 + ni * 16 + cc;
            float bsv = bias[col];
#pragma unroll
            for (int j = 0; j < 4; ++j) {
                int row = m0 + wr * 64 + mi * 16 + cr + j;
                float v = acc[mi][ni][j] + bsv;
                if (ACT) v = 0.5f * v * (1.0f + erff(v * 0.70710678118654752f));
                if (RES) v += res[(size_t)row * N + col];
                if (OBF) Cb[(size_t)row * N + col] = f2bf(v);
                else     Cf[(size_t)row * N + col] = v;
            }
        }
    }
}

// ---------------------------------------------------------------------------
// MFMA flash attention (bf16 in/out, fp32 softmax+accum).
// Block = 256 thr = 4 waves; wave owns 16 q-rows; block = 64 q of one (b,h).
// Per KV-tile(64): QK^T = mfma(K,Q) -> S^T frags (lane: 16 k-scores of one q,
// q=lane&15); softmax closes via shfl_xor 16/32; P->bf16 in per-wave LDS
// (stride 72: 2-way banks, 16B aligned); PV = mfma(P, Vt).
// K staged [k][d] with XOR-block swizzle, V staged transposed [d][k] same
// swizzle -> all frag reads are ds_read_b128 at <=2-way conflict.
// ---------------------------------------------------------------------------
__global__ __launch_bounds__(256, 2) void attn_mfma(const unsigned short* __restrict__ qkv,
                                                    unsigned short* __restrict__ o) {
    __shared__ unsigned short K_l[64 * 64];
    __shared__ unsigned short Vt_l[64 * 64];
    __shared__ unsigned short P_l[4 * 16 * 72];

    int tid = threadIdx.x;
    int lane = tid & 63, wid = tid >> 6;
    int g = lane >> 4;        // 0..3 lane-group
    int qi = lane & 15;       // q within wave (and k/d row within frag)
    int g4 = g * 4;
    int bh = blockIdx.y;
    int bb = bh >> 4, h = bh & 15;
    int bx = gridDim.x - 1 - blockIdx.x;   // heavy (long) blocks dispatch first
    int qblk0 = bx * 64;
    int wq0 = qblk0 + wid * 16;
    int qg = wq0 + qi;        // this lane's global q row (within T)

    // Q fragments (B-operand): Q[qg][kk*32 + g*8 + e], e=0..7
    const unsigned short* qptr = qkv + (size_t)(bb * T_ + qg) * 3072 + h * 64;
    bf16x8 qf0 = *(const bf16x8*)(qptr + g * 8);
    bf16x8 qf1 = *(const bf16x8*)(qptr + 32 + g * 8);

    f32x4 oacc[4] = {};       // O[q=g4+j][d=df*16+qi]
    float m = -INFINITY, l = 0.f;
    unsigned short* Pw = &P_l[wid * 16 * 72];

    for (int t = 0; t <= bx; ++t) {
        int kt0 = t * 64;
        __syncthreads();      // all waves done reading prev K/Vt
#pragma unroll
        for (int i = 0; i < 2; ++i) {
            int c = tid + i * 256;          // 512 chunks of 8 bf16
            int kr = c >> 3, d8 = c & 7;
            const unsigned short* src =
                qkv + (size_t)(bb * T_ + kt0 + kr) * 3072 + 1024 + h * 64 + d8 * 8;
            bf16x8 kv = *(const bf16x8*)src;
            bf16x8 vv = *(const bf16x8*)(src + 1024);
            *(bf16x8*)&K_l[kr * 64 + ((d8 ^ (kr & 7)) << 3)] = kv;
            int k8 = kr >> 3, klo = kr & 7;
#pragma unroll
            for (int e = 0; e < 8; ++e)
                Vt_l[(d8 * 8 + e) * 64 + ((k8 ^ e) << 3) + klo] = (unsigned short)vv[e];
        }
        __syncthreads();

        // ---- QK^T: S^T[k=f*16+g4+j][q=qi] ----
        f32x4 sf[4] = {};
#pragma unroll
        for (int f = 0; f < 4; ++f) {
            int krow = f * 16 + qi;
            int sw = krow & 7;
            bf16x8 ka0 = *(const bf16x8*)&K_l[krow * 64 + ((g ^ sw) << 3)];
            bf16x8 ka1 = *(const bf16x8*)&K_l[krow * 64 + (((4 + g) ^ sw) << 3)];
            sf[f] = __builtin_amdgcn_mfma_f32_16x16x32_bf16(ka0, qf0, sf[f], 0, 0, 0);
            sf[f] = __builtin_amdgcn_mfma_f32_16x16x32_bf16(ka1, qf1, sf[f], 0, 0, 0);
        }

        // ---- online softmax (per q = qi; replicated across 4 lane-groups) ----
        bool diag = (t == bx);
        float p[16];
        float tmax = -3e38f;
#pragma unroll
        for (int f = 0; f < 4; ++f)
#pragma unroll
            for (int j = 0; j < 4; ++j) {
                float s = sf[f][j] * 0.125f;   // 1/sqrt(64)
                if (diag && (kt0 + f * 16 + g4 + j > qg)) s = -3e38f;
                p[f * 4 + j] = s;
                tmax = fmaxf(tmax, s);
            }
        tmax = fmaxf(tmax, __shfl_xor(tmax, 16));
        tmax = fmaxf(tmax, __shfl_xor(tmax, 32));
        float mnew = fmaxf(m, tmax);
        float alpha = __expf(m - mnew);        // first tile: exp(-inf)=0
        m = mnew;
        float psum = 0.f;
#pragma unroll
        for (int i = 0; i < 16; ++i) { p[i] = __expf(p[i] - m); psum += p[i]; }
        psum += __shfl_xor(psum, 16);
        psum += __shfl_xor(psum, 32);
        l = l * alpha + psum;

        // rescale O rows q'=g4+j (alpha indexed by lane&15 -> shuffle)
        float a0 = __shfl(alpha, (lane & 48) | (g4 + 0));
        float a1 = __shfl(alpha, (lane & 48) | (g4 + 1));
        float a2 = __shfl(alpha, (lane & 48) | (g4 + 2));
        float a3 = __shfl(alpha, (lane & 48) | (g4 + 3));
#pragma unroll
        for (int df = 0; df < 4; ++df) {
            oacc[df][0] *= a0; oacc[df][1] *= a1;
            oacc[df][2] *= a2; oacc[df][3] *= a3;
        }

        // ---- P -> bf16 LDS (per-wave, stride 72) ----
#pragma unroll
        for (int f = 0; f < 4; ++f)
#pragma unroll
            for (int j = 0; j < 4; ++j)
                Pw[qi * 72 + f * 16 + g4 + j] = f2bf(p[f * 4 + j]);
        asm volatile("s_waitcnt lgkmcnt(0)" ::: "memory");

        // ---- PV: O += P[q][k] * V[k][d] ----
        bf16x8 pa0 = *(const bf16x8*)&Pw[qi * 72 + g * 8];
        bf16x8 pa1 = *(const bf16x8*)&Pw[qi * 72 + 32 + g * 8];
#pragma unroll
        for (int df = 0; df < 4; ++df) {
            int drow = df * 16 + qi;
            int sw = drow & 7;
            bf16x8 vb0 = *(const bf16x8*)&Vt_l[drow * 64 + ((g ^ sw) << 3)];
            bf16x8 vb1 = *(const bf16x8*)&Vt_l[drow * 64 + (((4 + g) ^ sw) << 3)];
            oacc[df] = __builtin_amdgcn_mfma_f32_16x16x32_bf16(pa0, vb0, oacc[df], 0, 0, 0);
            oacc[df] = __builtin_amdgcn_mfma_f32_16x16x32_bf16(pa1, vb1, oacc[df], 0, 0, 0);
        }
    }

    // ---- epilogue: O[q'][d] / l[q'] ----
    float linv[4];
#pragma unroll
    for (int j = 0; j < 4; ++j) {
        float lq = __shfl(l, (lane & 48) | (g4 + j));
        linv[j] = 1.0f / lq;
    }
#pragma unroll
    for (int df = 0; df < 4; ++df)
#pragma unroll
        for (int j = 0; j < 4; ++j) {
            int qrow = wq0 + g4 + j;
            int col = h * 64 + df * 16 + qi;
            o[(size_t)(bb * T_ + qrow) * 1024 + col] = f2bf(oacc[df][j] * linv[j]);
        }
}

// ---------------------------------------------------------------------------
// Workspace layout (104 MB peak, all bf16 intermediates):
//   [0,6) wq | [6,8) wo | [8,16) wf1 | [16,24) wf2
//   [24,72) qkv bf16 [8192,3072]  (phase 2: [24,40) ln2 bf16, [40,104) ff bf16)
//   [72,88) h bf16 (ln1 out), then attn out o bf16
//   x1 fp32 lives in d_out; fc2 accumulates into it in place.
// ---------------------------------------------------------------------------
extern "C" void kernel_launch(void* const* d_in, const int* in_sizes, int n_in,
                              void* d_out, int out_size, void* d_ws, size_t ws_size,
                              hipStream_t stream) {
    const float* x     = (const float*)d_in[0];
    const float* ln1_g = (const float*)d_in[1];
    const float* ln1_b = (const float*)d_in[2];
    const float* qkv_w = (const float*)d_in[3];
    const float* qkv_b = (const float*)d_in[4];
    const float* out_w = (const float*)d_in[5];
    const float* out_b = (const float*)d_in[6];
    const float* ln2_g = (const float*)d_in[7];
    const float* ln2_b = (const float*)d_in[8];
    const float* fc1_w = (const float*)d_in[9];
    const float* fc1_b = (const float*)d_in[10];
    const float* fc2_w = (const float*)d_in[11];
    const float* fc2_b = (const float*)d_in[12];
    float* out = (float*)d_out;

    const size_t MB = 1024 * 1024;
    char* wsc = (char*)d_ws;
    unsigned short* wq   = (unsigned short*)(wsc);
    unsigned short* wo   = (unsigned short*)(wsc + 6 * MB);
    unsigned short* wf1  = (unsigned short*)(wsc + 8 * MB);
    unsigned short* wf2  = (unsigned short*)(wsc + 16 * MB);
    unsigned short* qkvb = (unsigned short*)(wsc + 24 * MB);
    unsigned short* hb   = (unsigned short*)(wsc + 72 * MB);
    unsigned short* ln2b = (unsigned short*)(wsc + 24 * MB);
    unsigned short* ffb  = (unsigned short*)(wsc + 40 * MB);

    dim3 blk(256);

    cvt_kernel<<<1024, blk, 0, stream>>>(qkv_w, wq, 3 * C_ * C_ / 4);
    cvt_kernel<<<1024, blk, 0, stream>>>(out_w, wo, C_ * C_ / 4);
    cvt_kernel<<<1024, blk, 0, stream>>>(fc1_w, wf1, FF_ * C_ / 4);
    cvt_kernel<<<1024, blk, 0, stream>>>(fc2_w, wf2, FF_ * C_ / 4);

    // 1. h = LN1(x) -> bf16
    ln_kernel<<<BT_, blk, 0, stream>>>(x, ln1_g, ln1_b, hb);
    // 2. qkv = h @ qkv_w^T + b -> bf16 [8192,3072]
    gemm_mfma<0, 0, 1><<<dim3(24, 64), blk, 0, stream>>>(hb, wq, qkv_b, nullptr,
                                                         nullptr, qkvb, BT_, 3 * C_, C_);
    // 3. o = attention(qkv) -> bf16
    attn_mfma<<<dim3(32, 64), blk, 0, stream>>>(qkvb, hb);
    // 4. x1 = x + o @ out_w^T + b -> d_out fp32
    gemm_mfma<0, 1, 0><<<dim3(8, 64), blk, 0, stream>>>(hb, wo, out_b, x,
                                                        out, nullptr, BT_, C_, C_);
    // 5. h2 = LN2(x1) -> bf16
    ln_kernel<<<BT_, blk, 0, stream>>>(out, ln2_g, ln2_b, ln2b);
    // 6. ff = gelu(h2 @ fc1_w^T + b) -> bf16 [8192,4096]
    gemm_mfma<1, 0, 1><<<dim3(32, 64), blk, 0, stream>>>(ln2b, wf1, fc1_b, nullptr,
                                                         nullptr, ffb, BT_, FF_, C_);
    // 7. out = x1 + ff @ fc2_w^T + b (in place on d_out)
    gemm_mfma<0, 1, 0><<<dim3(8, 64), blk, 0, stream>>>(ffb, wf2, fc2_b, out,
                                                        out, nullptr, BT_, C_, FF_);
}

// Round 6
// 626.079 us; speedup vs baseline: 6.9716x; 1.0711x over previous
//
#include <hip/hip_runtime.h>
#include <cmath>

#define B_ 4
#define T_ 2048
#define C_ 1024
#define H_ 16
#define D_ 64
#define FF_ 4096
#define BT_ (B_ * T_)

typedef __attribute__((ext_vector_type(8))) short bf16x8;   // 8 bf16 = 4 VGPRs
typedef __attribute__((ext_vector_type(4))) float f32x4;

// fp32 -> bf16 round-to-nearest-even
__device__ __forceinline__ unsigned short f2bf(float f) {
    union { float f; unsigned int u; } c; c.f = f;
    unsigned int u = c.u + 0x7FFFu + ((c.u >> 16) & 1u);
    return (unsigned short)(u >> 16);
}
__device__ __forceinline__ float bf2f(unsigned short u) {
    union { unsigned int u; float f; } c; c.u = ((unsigned int)u) << 16;
    return c.f;
}

// async global->LDS, 16B per lane. LDS dest is wave-uniform base + lane*16.
__device__ __forceinline__ void gload_lds16(const unsigned short* g, unsigned short* l) {
    __builtin_amdgcn_global_load_lds((const __attribute__((address_space(1))) void*)g,
                                     (__attribute__((address_space(3))) void*)l, 16, 0, 0);
}

// ---------------------------------------------------------------------------
// fp32 -> bf16 convert (weights), grid-stride, float4 in / ushort4 out.
// ---------------------------------------------------------------------------
__global__ __launch_bounds__(256) void cvt_kernel(const float* __restrict__ src,
                                                  unsigned short* __restrict__ dst, int n4) {
    int i = blockIdx.x * 256 + threadIdx.x;
    int stride = gridDim.x * 256;
    for (; i < n4; i += stride) {
        float4 v = ((const float4*)src)[i];
        ushort4 o;
        o.x = f2bf(v.x); o.y = f2bf(v.y); o.z = f2bf(v.z); o.w = f2bf(v.w);
        ((ushort4*)dst)[i] = o;
    }
}

// ---------------------------------------------------------------------------
// LayerNorm: one block per row (1024 floats), 256 threads; bf16 output.
// ---------------------------------------------------------------------------
__global__ __launch_bounds__(256) void ln_kernel(const float* __restrict__ x,
                                                 const float* __restrict__ g,
                                                 const float* __restrict__ b,
                                                 unsigned short* __restrict__ y) {
    __shared__ float ls[4], lq[4];
    __shared__ float mean_s, rstd_s;
    int row = blockIdx.x;
    const float4* xr = (const float4*)(x + (size_t)row * C_);
    float4 v = xr[threadIdx.x];
    float s = v.x + v.y + v.z + v.w;
    float sq = v.x * v.x + v.y * v.y + v.z * v.z + v.w * v.w;
#pragma unroll
    for (int off = 32; off > 0; off >>= 1) {
        s += __shfl_down(s, off);
        sq += __shfl_down(sq, off);
    }
    int wid = threadIdx.x >> 6, lane = threadIdx.x & 63;
    if (lane == 0) { ls[wid] = s; lq[wid] = sq; }
    __syncthreads();
    if (threadIdx.x == 0) {
        float S = ls[0] + ls[1] + ls[2] + ls[3];
        float Q = lq[0] + lq[1] + lq[2] + lq[3];
        float mean = S * (1.0f / C_);
        float var = Q * (1.0f / C_) - mean * mean;
        mean_s = mean;
        rstd_s = 1.0f / sqrtf(var + 1e-5f);
    }
    __syncthreads();
    float mean = mean_s, rstd = rstd_s;
    float4 gv = ((const float4*)g)[threadIdx.x];
    float4 bv = ((const float4*)b)[threadIdx.x];
    ushort4 o;
    o.x = f2bf((v.x - mean) * rstd * gv.x + bv.x);
    o.y = f2bf((v.y - mean) * rstd * gv.y + bv.y);
    o.z = f2bf((v.z - mean) * rstd * gv.z + bv.z);
    o.w = f2bf((v.w - mean) * rstd * gv.w + bv.w);
    ((ushort4*)(y + (size_t)row * C_))[threadIdx.x] = o;
}

// ---------------------------------------------------------------------------
// bf16 MFMA GEMM (m97 structure) + XCD-aware block swizzle (T1).
// C[M,N] = A[M,K] @ W[N,K]^T (+bias/gelu/res). 128x128 tile, BK=32, 4 waves.
// ---------------------------------------------------------------------------
template <int ACT, int RES, int OBF>
__global__ __launch_bounds__(256, 2) void gemm_mfma(
        const unsigned short* __restrict__ A,
        const unsigned short* __restrict__ W,
        const float* __restrict__ bias,
        const float* __restrict__ res,
        float* __restrict__ Cf,
        unsigned short* __restrict__ Cb,
        int M, int N, int K) {
    __shared__ unsigned short As[128 * 32];
    __shared__ unsigned short Bs[128 * 32];
    int tid = threadIdx.x;
    int lane = tid & 63, wid = tid >> 6;
    int wr = wid >> 1, wc = wid & 1;

    // XCD swizzle: all grids here have nwg % 8 == 0 -> simple bijective remap.
    int gx = gridDim.x;
    int bid = blockIdx.y * gx + blockIdx.x;
    int cpx = (gx * gridDim.y) >> 3;
    int swz = (bid & 7) * cpx + (bid >> 3);
    int m0 = (swz / gx) * 128, n0 = (swz % gx) * 128;

    const unsigned short* Ag = A + (size_t)(m0 + (tid >> 2)) * K + (tid & 3) * 8;
    const unsigned short* Wg = W + (size_t)(n0 + (tid >> 2)) * K + (tid & 3) * 8;
    unsigned short* Al0 = As + (size_t)(wid * 64) * 8;
    unsigned short* Al1 = As + (size_t)(256 + wid * 64) * 8;
    unsigned short* Bl0 = Bs + (size_t)(wid * 64) * 8;
    unsigned short* Bl1 = Bs + (size_t)(256 + wid * 64) * 8;

    f32x4 acc[4][4] = {};

    int ar = lane & 15, ac8 = (lane >> 4) * 8;
    int aoffA = (wr * 64 + ar) * 32 + ac8;
    int aoffB = (wc * 64 + ar) * 32 + ac8;

    for (int k0 = 0; k0 < K; k0 += 32) {
        __syncthreads();
        gload_lds16(Ag, Al0);
        gload_lds16(Ag + (size_t)64 * K, Al1);
        gload_lds16(Wg, Bl0);
        gload_lds16(Wg + (size_t)64 * K, Bl1);
        Ag += 32; Wg += 32;
        __syncthreads();
        bf16x8 af[4], bw[4];
#pragma unroll
        for (int i = 0; i < 4; ++i) {
            af[i] = *(const bf16x8*)&As[aoffA + i * 16 * 32];
            bw[i] = *(const bf16x8*)&Bs[aoffB + i * 16 * 32];
        }
#pragma unroll
        for (int mi = 0; mi < 4; ++mi)
#pragma unroll
            for (int ni = 0; ni < 4; ++ni)
                acc[mi][ni] = __builtin_amdgcn_mfma_f32_16x16x32_bf16(
                    af[mi], bw[ni], acc[mi][ni], 0, 0, 0);
    }

    int cr = (lane >> 4) * 4;
    int cc = lane & 15;
#pragma unroll
    for (int mi = 0; mi < 4; ++mi) {
#pragma unroll
        for (int ni = 0; ni < 4; ++ni) {
            int col = n0 + wc * 64 + ni * 16 + cc;
            float bsv = bias[col];
#pragma unroll
            for (int j = 0; j < 4; ++j) {
                int row = m0 + wr * 64 + mi * 16 + cr + j;
                float v = acc[mi][ni][j] + bsv;
                if (ACT) v = 0.5f * v * (1.0f + erff(v * 0.70710678118654752f));
                if (RES) v += res[(size_t)row * N + col];
                if (OBF) Cb[(size_t)row * N + col] = f2bf(v);
                else     Cf[(size_t)row * N + col] = v;
            }
        }
    }
}

// ---------------------------------------------------------------------------
// MFMA flash attention v3. Block = 4 waves, 128 q of one (b,h); each wave owns
// 32 q as TWO 16-row fragment sets (halves K/V staging + softmax fixed cost
// per unit work vs v2). Vt store swizzle now includes d8 (octet = k8^e^d8):
// all 64 lanes of each scalar store hit distinct addr mod 64 -> 2-way = free
// (was 8-way, 3.35e7 conflicts/dispatch). Fully-masked waves skip compute.
// ---------------------------------------------------------------------------
__device__ __forceinline__ void attn_qset(
        const unsigned short* K_l, const unsigned short* Vt_l, unsigned short* Pw,
        const bf16x8& qfa, const bf16x8& qfb,
        float& m, float& l, f32x4* oacc,
        int g, int qi, int g4, int lane, int prow, int qg, int kt0, bool diag) {
    // ---- QK^T: S^T[k=f*16+g4+j][q=qi] ----
    f32x4 sf[4] = {};
#pragma unroll
    for (int f = 0; f < 4; ++f) {
        int krow = f * 16 + qi;
        int sw = krow & 7;
        bf16x8 ka0 = *(const bf16x8*)&K_l[krow * 64 + ((g ^ sw) << 3)];
        bf16x8 ka1 = *(const bf16x8*)&K_l[krow * 64 + (((4 + g) ^ sw) << 3)];
        sf[f] = __builtin_amdgcn_mfma_f32_16x16x32_bf16(ka0, qfa, sf[f], 0, 0, 0);
        sf[f] = __builtin_amdgcn_mfma_f32_16x16x32_bf16(ka1, qfb, sf[f], 0, 0, 0);
    }
    // ---- online softmax (per q = qi) ----
    float p[16];
    float tmax = -3e38f;
#pragma unroll
    for (int f = 0; f < 4; ++f)
#pragma unroll
        for (int j = 0; j < 4; ++j) {
            float s = sf[f][j] * 0.125f;   // 1/sqrt(64)
            if (diag && (kt0 + f * 16 + g4 + j > qg)) s = -3e38f;
            p[f * 4 + j] = s;
            tmax = fmaxf(tmax, s);
        }
    tmax = fmaxf(tmax, __shfl_xor(tmax, 16));
    tmax = fmaxf(tmax, __shfl_xor(tmax, 32));
    float mnew = fmaxf(m, tmax);
    float alpha = __expf(m - mnew);
    m = mnew;
    float psum = 0.f;
#pragma unroll
    for (int i = 0; i < 16; ++i) { p[i] = __expf(p[i] - m); psum += p[i]; }
    psum += __shfl_xor(psum, 16);
    psum += __shfl_xor(psum, 32);
    l = l * alpha + psum;

    float a0 = __shfl(alpha, (lane & 48) | (g4 + 0));
    float a1 = __shfl(alpha, (lane & 48) | (g4 + 1));
    float a2 = __shfl(alpha, (lane & 48) | (g4 + 2));
    float a3 = __shfl(alpha, (lane & 48) | (g4 + 3));
#pragma unroll
    for (int df = 0; df < 4; ++df) {
        oacc[df][0] *= a0; oacc[df][1] *= a1;
        oacc[df][2] *= a2; oacc[df][3] *= a3;
    }

    // ---- P -> bf16 LDS (stride 72: 2-way banks) ----
#pragma unroll
    for (int f = 0; f < 4; ++f)
#pragma unroll
        for (int j = 0; j < 4; ++j)
            Pw[prow * 72 + f * 16 + g4 + j] = f2bf(p[f * 4 + j]);
    asm volatile("s_waitcnt lgkmcnt(0)" ::: "memory");

    // ---- PV: O += P[q][k] * V[k][d] ----
    bf16x8 pa0 = *(const bf16x8*)&Pw[prow * 72 + g * 8];
    bf16x8 pa1 = *(const bf16x8*)&Pw[prow * 72 + 32 + g * 8];
#pragma unroll
    for (int df = 0; df < 4; ++df) {
        int drow = df * 16 + qi;
        int sw = ((drow & 7) ^ (drow >> 3)) & 7;
        bf16x8 vb0 = *(const bf16x8*)&Vt_l[drow * 64 + ((g ^ sw) << 3)];
        bf16x8 vb1 = *(const bf16x8*)&Vt_l[drow * 64 + (((4 + g) ^ sw) << 3)];
        oacc[df] = __builtin_amdgcn_mfma_f32_16x16x32_bf16(pa0, vb0, oacc[df], 0, 0, 0);
        oacc[df] = __builtin_amdgcn_mfma_f32_16x16x32_bf16(pa1, vb1, oacc[df], 0, 0, 0);
    }
}

__global__ __launch_bounds__(256, 2) void attn_mfma(const unsigned short* __restrict__ qkv,
                                                    unsigned short* __restrict__ o) {
    __shared__ unsigned short K_l[64 * 64];
    __shared__ unsigned short Vt_l[64 * 64];
    __shared__ unsigned short P_l[4 * 32 * 72];

    int tid = threadIdx.x;
    int lane = tid & 63, wid = tid >> 6;
    int g = lane >> 4;
    int qi = lane & 15;
    int g4 = g * 4;
    int bh = blockIdx.y;
    int bb = bh >> 4, h = bh & 15;
    int bx = (int)gridDim.x - 1 - blockIdx.x;   // heavy blocks dispatch first
    int qblk0 = bx * 128;
    int wq0 = qblk0 + wid * 32;                 // wave owns q [wq0, wq0+32)
    int qg0 = wq0 + qi;
    int qg1 = wq0 + 16 + qi;

    const unsigned short* qp0 = qkv + (size_t)(bb * T_ + qg0) * 3072 + h * 64;
    const unsigned short* qp1 = qkv + (size_t)(bb * T_ + qg1) * 3072 + h * 64;
    bf16x8 qf0a = *(const bf16x8*)(qp0 + g * 8);
    bf16x8 qf0b = *(const bf16x8*)(qp0 + 32 + g * 8);
    bf16x8 qf1a = *(const bf16x8*)(qp1 + g * 8);
    bf16x8 qf1b = *(const bf16x8*)(qp1 + 32 + g * 8);

    f32x4 oacc0[4] = {}, oacc1[4] = {};
    float m0 = -INFINITY, l0 = 0.f, m1 = -INFINITY, l1 = 0.f;
    unsigned short* Pw = &P_l[wid * 32 * 72];

    int ntiles = 2 * bx + 2;
    for (int t = 0; t < ntiles; ++t) {
        int kt0 = t * 64;
        __syncthreads();      // all waves done reading prev K/Vt
#pragma unroll
        for (int i = 0; i < 2; ++i) {
            int c = tid + i * 256;          // 512 chunks of 8 bf16
            int kr = c >> 3, d8 = c & 7;
            const unsigned short* src =
                qkv + (size_t)(bb * T_ + kt0 + kr) * 3072 + 1024 + h * 64 + d8 * 8;
            bf16x8 kv = *(const bf16x8*)src;
            bf16x8 vv = *(const bf16x8*)(src + 1024);
            *(bf16x8*)&K_l[kr * 64 + ((d8 ^ (kr & 7)) << 3)] = kv;
            int k8 = kr >> 3, klo = kr & 7;
#pragma unroll
            for (int e = 0; e < 8; ++e)
                Vt_l[(d8 * 8 + e) * 64 + (((k8 ^ e ^ d8) & 7) << 3) + klo] =
                    (unsigned short)vv[e];
        }
        __syncthreads();
        if (kt0 > wq0 + 31) continue;   // wave fully masked (no barrier inside)
        bool diag = (t >= 2 * bx);
        attn_qset(K_l, Vt_l, Pw, qf0a, qf0b, m0, l0, oacc0,
                  g, qi, g4, lane, qi, qg0, kt0, diag);
        attn_qset(K_l, Vt_l, Pw, qf1a, qf1b, m1, l1, oacc1,
                  g, qi, g4, lane, 16 + qi, qg1, kt0, diag);
    }

    // ---- epilogue ----
    float linv0[4], linv1[4];
#pragma unroll
    for (int j = 0; j < 4; ++j) {
        linv0[j] = 1.0f / __shfl(l0, (lane & 48) | (g4 + j));
        linv1[j] = 1.0f / __shfl(l1, (lane & 48) | (g4 + j));
    }
#pragma unroll
    for (int df = 0; df < 4; ++df)
#pragma unroll
        for (int j = 0; j < 4; ++j) {
            int col = h * 64 + df * 16 + qi;
            int qr0 = wq0 + g4 + j;
            int qr1 = wq0 + 16 + g4 + j;
            o[(size_t)(bb * T_ + qr0) * 1024 + col] = f2bf(oacc0[df][j] * linv0[j]);
            o[(size_t)(bb * T_ + qr1) * 1024 + col] = f2bf(oacc1[df][j] * linv1[j]);
        }
}

// ---------------------------------------------------------------------------
// Workspace layout (104 MB peak, all bf16 intermediates):
//   [0,6) wq | [6,8) wo | [8,16) wf1 | [16,24) wf2
//   [24,72) qkv bf16 [8192,3072]  (phase 2: [24,40) ln2 bf16, [40,104) ff bf16)
//   [72,88) h bf16 (ln1 out), then attn out o bf16
//   x1 fp32 lives in d_out; fc2 accumulates into it in place.
// ---------------------------------------------------------------------------
extern "C" void kernel_launch(void* const* d_in, const int* in_sizes, int n_in,
                              void* d_out, int out_size, void* d_ws, size_t ws_size,
                              hipStream_t stream) {
    const float* x     = (const float*)d_in[0];
    const float* ln1_g = (const float*)d_in[1];
    const float* ln1_b = (const float*)d_in[2];
    const float* qkv_w = (const float*)d_in[3];
    const float* qkv_b = (const float*)d_in[4];
    const float* out_w = (const float*)d_in[5];
    const float* out_b = (const float*)d_in[6];
    const float* ln2_g = (const float*)d_in[7];
    const float* ln2_b = (const float*)d_in[8];
    const float* fc1_w = (const float*)d_in[9];
    const float* fc1_b = (const float*)d_in[10];
    const float* fc2_w = (const float*)d_in[11];
    const float* fc2_b = (const float*)d_in[12];
    float* out = (float*)d_out;

    const size_t MB = 1024 * 1024;
    char* wsc = (char*)d_ws;
    unsigned short* wq   = (unsigned short*)(wsc);
    unsigned short* wo   = (unsigned short*)(wsc + 6 * MB);
    unsigned short* wf1  = (unsigned short*)(wsc + 8 * MB);
    unsigned short* wf2  = (unsigned short*)(wsc + 16 * MB);
    unsigned short* qkvb = (unsigned short*)(wsc + 24 * MB);
    unsigned short* hb   = (unsigned short*)(wsc + 72 * MB);
    unsigned short* ln2b = (unsigned short*)(wsc + 24 * MB);
    unsigned short* ffb  = (unsigned short*)(wsc + 40 * MB);

    dim3 blk(256);

    cvt_kernel<<<1024, blk, 0, stream>>>(qkv_w, wq, 3 * C_ * C_ / 4);
    cvt_kernel<<<1024, blk, 0, stream>>>(out_w, wo, C_ * C_ / 4);
    cvt_kernel<<<1024, blk, 0, stream>>>(fc1_w, wf1, FF_ * C_ / 4);
    cvt_kernel<<<1024, blk, 0, stream>>>(fc2_w, wf2, FF_ * C_ / 4);

    // 1. h = LN1(x) -> bf16
    ln_kernel<<<BT_, blk, 0, stream>>>(x, ln1_g, ln1_b, hb);
    // 2. qkv = h @ qkv_w^T + b -> bf16 [8192,3072]
    gemm_mfma<0, 0, 1><<<dim3(24, 64), blk, 0, stream>>>(hb, wq, qkv_b, nullptr,
                                                         nullptr, qkvb, BT_, 3 * C_, C_);
    // 3. o = attention(qkv) -> bf16
    attn_mfma<<<dim3(16, 64), blk, 0, stream>>>(qkvb, hb);
    // 4. x1 = x + o @ out_w^T + b -> d_out fp32
    gemm_mfma<0, 1, 0><<<dim3(8, 64), blk, 0, stream>>>(hb, wo, out_b, x,
                                                        out, nullptr, BT_, C_, C_);
    // 5. h2 = LN2(x1) -> bf16
    ln_kernel<<<BT_, blk, 0, stream>>>(out, ln2_g, ln2_b, ln2b);
    // 6. ff = gelu(h2 @ fc1_w^T + b) -> bf16 [8192,4096]
    gemm_mfma<1, 0, 1><<<dim3(32, 64), blk, 0, stream>>>(ln2b, wf1, fc1_b, nullptr,
                                                         nullptr, ffb, BT_, FF_, C_);
    // 7. out = x1 + ff @ fc2_w^T + b (in place on d_out)
    gemm_mfma<0, 1, 0><<<dim3(8, 64), blk, 0, stream>>>(ffb, wf2, fc2_b, out,
                                                        out, nullptr, BT_, C_, FF_);
}

// Round 9
// 531.757 us; speedup vs baseline: 8.2083x; 1.1774x over previous
//
#include <hip/hip_runtime.h>
#include <cmath>

#define B_ 4
#define T_ 2048
#define C_ 1024
#define H_ 16
#define D_ 64
#define FF_ 4096
#define BT_ (B_ * T_)

typedef __attribute__((ext_vector_type(8))) short bf16x8;   // 8 bf16 = 4 VGPRs
typedef __attribute__((ext_vector_type(4))) float f32x4;

// fp32 -> bf16 round-to-nearest-even
__device__ __forceinline__ unsigned short f2bf(float f) {
    union { float f; unsigned int u; } c; c.f = f;
    unsigned int u = c.u + 0x7FFFu + ((c.u >> 16) & 1u);
    return (unsigned short)(u >> 16);
}
__device__ __forceinline__ float bf2f(unsigned short u) {
    union { unsigned int u; float f; } c; c.u = ((unsigned int)u) << 16;
    return c.f;
}

// async global->LDS, 16B per lane. LDS dest is wave-uniform base + lane*16.
__device__ __forceinline__ void gload_lds16(const unsigned short* g, unsigned short* l) {
    __builtin_amdgcn_global_load_lds((const __attribute__((address_space(1))) void*)g,
                                     (__attribute__((address_space(3))) void*)l, 16, 0, 0);
}

// ---------------------------------------------------------------------------
// Merged fp32 -> bf16 weight convert: all four weight tensors in one launch.
// Segment boundaries in float4 units.
// ---------------------------------------------------------------------------
__global__ __launch_bounds__(256) void cvt_all_kernel(
        const float* __restrict__ s0, unsigned short* __restrict__ d0,   // qkv_w 786432
        const float* __restrict__ s1, unsigned short* __restrict__ d1,   // out_w 262144
        const float* __restrict__ s2, unsigned short* __restrict__ d2,   // fc1_w 1048576
        const float* __restrict__ s3, unsigned short* __restrict__ d3) { // fc2_w 1048576
    const int N0 = 786432, N1 = 262144, N2 = 1048576, N3 = 1048576;
    int i = blockIdx.x * 256 + threadIdx.x;
    int stride = gridDim.x * 256;
    for (; i < N0 + N1 + N2 + N3; i += stride) {
        const float* src; unsigned short* dst; int k;
        if (i < N0)                { src = s0; dst = d0; k = i; }
        else if (i < N0 + N1)      { src = s1; dst = d1; k = i - N0; }
        else if (i < N0 + N1 + N2) { src = s2; dst = d2; k = i - N0 - N1; }
        else                       { src = s3; dst = d3; k = i - N0 - N1 - N2; }
        float4 v = ((const float4*)src)[k];
        ushort4 o;
        o.x = f2bf(v.x); o.y = f2bf(v.y); o.z = f2bf(v.z); o.w = f2bf(v.w);
        ((ushort4*)dst)[k] = o;
    }
}

// ---------------------------------------------------------------------------
// LayerNorm: one block per row (1024 floats), 256 threads; bf16 output.
// ---------------------------------------------------------------------------
__global__ __launch_bounds__(256) void ln_kernel(const float* __restrict__ x,
                                                 const float* __restrict__ g,
                                                 const float* __restrict__ b,
                                                 unsigned short* __restrict__ y) {
    __shared__ float ls[4], lq[4];
    __shared__ float mean_s, rstd_s;
    int row = blockIdx.x;
    const float4* xr = (const float4*)(x + (size_t)row * C_);
    float4 v = xr[threadIdx.x];
    float s = v.x + v.y + v.z + v.w;
    float sq = v.x * v.x + v.y * v.y + v.z * v.z + v.w * v.w;
#pragma unroll
    for (int off = 32; off > 0; off >>= 1) {
        s += __shfl_down(s, off);
        sq += __shfl_down(sq, off);
    }
    int wid = threadIdx.x >> 6, lane = threadIdx.x & 63;
    if (lane == 0) { ls[wid] = s; lq[wid] = sq; }
    __syncthreads();
    if (threadIdx.x == 0) {
        float S = ls[0] + ls[1] + ls[2] + ls[3];
        float Q = lq[0] + lq[1] + lq[2] + lq[3];
        float mean = S * (1.0f / C_);
        float var = Q * (1.0f / C_) - mean * mean;
        mean_s = mean;
        rstd_s = 1.0f / sqrtf(var + 1e-5f);
    }
    __syncthreads();
    float mean = mean_s, rstd = rstd_s;
    float4 gv = ((const float4*)g)[threadIdx.x];
    float4 bv = ((const float4*)b)[threadIdx.x];
    ushort4 o;
    o.x = f2bf((v.x - mean) * rstd * gv.x + bv.x);
    o.y = f2bf((v.y - mean) * rstd * gv.y + bv.y);
    o.z = f2bf((v.z - mean) * rstd * gv.z + bv.z);
    o.w = f2bf((v.w - mean) * rstd * gv.w + bv.w);
    ((ushort4*)(y + (size_t)row * C_))[threadIdx.x] = o;
}

// ---------------------------------------------------------------------------
// bf16 MFMA GEMM (m97 structure) + XCD-aware block swizzle (T1).
// C[M,N] = A[M,K] @ W[N,K]^T (+bias/gelu/res). 128x128 tile, BK=32, 4 waves.
// ---------------------------------------------------------------------------
template <int ACT, int RES, int OBF>
__global__ __launch_bounds__(256, 2) void gemm_mfma(
        const unsigned short* __restrict__ A,
        const unsigned short* __restrict__ W,
        const float* __restrict__ bias,
        const float* __restrict__ res,
        float* __restrict__ Cf,
        unsigned short* __restrict__ Cb,
        int M, int N, int K) {
    __shared__ unsigned short As[128 * 32];
    __shared__ unsigned short Bs[128 * 32];
    int tid = threadIdx.x;
    int lane = tid & 63, wid = tid >> 6;
    int wr = wid >> 1, wc = wid & 1;

    // XCD swizzle: all grids here have nwg % 8 == 0 -> simple bijective remap.
    int gx = gridDim.x;
    int bid = blockIdx.y * gx + blockIdx.x;
    int cpx = (gx * gridDim.y) >> 3;
    int swz = (bid & 7) * cpx + (bid >> 3);
    int m0 = (swz / gx) * 128, n0 = (swz % gx) * 128;

    const unsigned short* Ag = A + (size_t)(m0 + (tid >> 2)) * K + (tid & 3) * 8;
    const unsigned short* Wg = W + (size_t)(n0 + (tid >> 2)) * K + (tid & 3) * 8;
    unsigned short* Al0 = As + (size_t)(wid * 64) * 8;
    unsigned short* Al1 = As + (size_t)(256 + wid * 64) * 8;
    unsigned short* Bl0 = Bs + (size_t)(wid * 64) * 8;
    unsigned short* Bl1 = Bs + (size_t)(256 + wid * 64) * 8;

    f32x4 acc[4][4] = {};

    int ar = lane & 15, ac8 = (lane >> 4) * 8;
    int aoffA = (wr * 64 + ar) * 32 + ac8;
    int aoffB = (wc * 64 + ar) * 32 + ac8;

    for (int k0 = 0; k0 < K; k0 += 32) {
        __syncthreads();
        gload_lds16(Ag, Al0);
        gload_lds16(Ag + (size_t)64 * K, Al1);
        gload_lds16(Wg, Bl0);
        gload_lds16(Wg + (size_t)64 * K, Bl1);
        Ag += 32; Wg += 32;
        __syncthreads();
        bf16x8 af[4], bw[4];
#pragma unroll
        for (int i = 0; i < 4; ++i) {
            af[i] = *(const bf16x8*)&As[aoffA + i * 16 * 32];
            bw[i] = *(const bf16x8*)&Bs[aoffB + i * 16 * 32];
        }
#pragma unroll
        for (int mi = 0; mi < 4; ++mi)
#pragma unroll
            for (int ni = 0; ni < 4; ++ni)
                acc[mi][ni] = __builtin_amdgcn_mfma_f32_16x16x32_bf16(
                    af[mi], bw[ni], acc[mi][ni], 0, 0, 0);
    }

    int cr = (lane >> 4) * 4;
    int cc = lane & 15;
#pragma unroll
    for (int mi = 0; mi < 4; ++mi) {
#pragma unroll
        for (int ni = 0; ni < 4; ++ni) {
            int col = n0 + wc * 64 + ni * 16 + cc;
            float bsv = bias[col];
#pragma unroll
            for (int j = 0; j < 4; ++j) {
                int row = m0 + wr * 64 + mi * 16 + cr + j;
                float v = acc[mi][ni][j] + bsv;
                if (ACT) v = 0.5f * v * (1.0f + erff(v * 0.70710678118654752f));
                if (RES) v += res[(size_t)row * N + col];
                if (OBF) Cb[(size_t)row * N + col] = f2bf(v);
                else     Cf[(size_t)row * N + col] = v;
            }
        }
    }
}

// ---------------------------------------------------------------------------
// MFMA flash attention v4: causal load-balance pairing.
// Block = 4 waves; processes TWO 128-query blocks, p and 15-p, sequentially:
// tile count = (2p+2)+(2(15-p)+2) = 34, constant -> zero CU imbalance
// (v3's grid had stride-256 CU aliasing stacking 4 same-length blocks, ~1.9x
// critical-path inflation). Grid 8x64 = 512 blocks = 2/CU, all resident.
// ---------------------------------------------------------------------------
__device__ __forceinline__ void attn_qset(
        const unsigned short* K_l, const unsigned short* Vt_l, unsigned short* Pw,
        const bf16x8& qfa, const bf16x8& qfb,
        float& m, float& l, f32x4* oacc,
        int g, int qi, int g4, int lane, int prow, int qg, int kt0, bool diag) {
    // ---- QK^T: S^T[k=f*16+g4+j][q=qi] ----
    f32x4 sf[4] = {};
#pragma unroll
    for (int f = 0; f < 4; ++f) {
        int krow = f * 16 + qi;
        int sw = krow & 7;
        bf16x8 ka0 = *(const bf16x8*)&K_l[krow * 64 + ((g ^ sw) << 3)];
        bf16x8 ka1 = *(const bf16x8*)&K_l[krow * 64 + (((4 + g) ^ sw) << 3)];
        sf[f] = __builtin_amdgcn_mfma_f32_16x16x32_bf16(ka0, qfa, sf[f], 0, 0, 0);
        sf[f] = __builtin_amdgcn_mfma_f32_16x16x32_bf16(ka1, qfb, sf[f], 0, 0, 0);
    }
    // ---- online softmax (per q = qi) ----
    float p[16];
    float tmax = -3e38f;
#pragma unroll
    for (int f = 0; f < 4; ++f)
#pragma unroll
        for (int j = 0; j < 4; ++j) {
            float s = sf[f][j] * 0.125f;   // 1/sqrt(64)
            if (diag && (kt0 + f * 16 + g4 + j > qg)) s = -3e38f;
            p[f * 4 + j] = s;
            tmax = fmaxf(tmax, s);
        }
    tmax = fmaxf(tmax, __shfl_xor(tmax, 16));
    tmax = fmaxf(tmax, __shfl_xor(tmax, 32));
    float mnew = fmaxf(m, tmax);
    float alpha = __expf(m - mnew);
    m = mnew;
    float psum = 0.f;
#pragma unroll
    for (int i = 0; i < 16; ++i) { p[i] = __expf(p[i] - m); psum += p[i]; }
    psum += __shfl_xor(psum, 16);
    psum += __shfl_xor(psum, 32);
    l = l * alpha + psum;

    float a0 = __shfl(alpha, (lane & 48) | (g4 + 0));
    float a1 = __shfl(alpha, (lane & 48) | (g4 + 1));
    float a2 = __shfl(alpha, (lane & 48) | (g4 + 2));
    float a3 = __shfl(alpha, (lane & 48) | (g4 + 3));
#pragma unroll
    for (int df = 0; df < 4; ++df) {
        oacc[df][0] *= a0; oacc[df][1] *= a1;
        oacc[df][2] *= a2; oacc[df][3] *= a3;
    }

    // ---- P -> bf16 LDS (stride 72: 2-way banks) ----
#pragma unroll
    for (int f = 0; f < 4; ++f)
#pragma unroll
        for (int j = 0; j < 4; ++j)
            Pw[prow * 72 + f * 16 + g4 + j] = f2bf(p[f * 4 + j]);
    asm volatile("s_waitcnt lgkmcnt(0)" ::: "memory");

    // ---- PV: O += P[q][k] * V[k][d] ----
    bf16x8 pa0 = *(const bf16x8*)&Pw[prow * 72 + g * 8];
    bf16x8 pa1 = *(const bf16x8*)&Pw[prow * 72 + 32 + g * 8];
#pragma unroll
    for (int df = 0; df < 4; ++df) {
        int drow = df * 16 + qi;
        int sw = ((drow & 7) ^ (drow >> 3)) & 7;
        bf16x8 vb0 = *(const bf16x8*)&Vt_l[drow * 64 + ((g ^ sw) << 3)];
        bf16x8 vb1 = *(const bf16x8*)&Vt_l[drow * 64 + (((4 + g) ^ sw) << 3)];
        oacc[df] = __builtin_amdgcn_mfma_f32_16x16x32_bf16(pa0, vb0, oacc[df], 0, 0, 0);
        oacc[df] = __builtin_amdgcn_mfma_f32_16x16x32_bf16(pa1, vb1, oacc[df], 0, 0, 0);
    }
}

__global__ __launch_bounds__(256, 2) void attn_mfma(const unsigned short* __restrict__ qkv,
                                                    unsigned short* __restrict__ o) {
    __shared__ unsigned short K_l[64 * 64];
    __shared__ unsigned short Vt_l[64 * 64];
    __shared__ unsigned short P_l[4 * 32 * 72];

    int tid = threadIdx.x;
    int lane = tid & 63, wid = tid >> 6;
    int g = lane >> 4;
    int qi = lane & 15;
    int g4 = g * 4;
    int bh = blockIdx.y;
    int bb = bh >> 4, h = bh & 15;
    int pb = blockIdx.x;                        // 0..7 pair index

    for (int half = 0; half < 2; ++half) {
        int qblk = half ? (15 - pb) : pb;       // paired: tiles sum to 34
        int wq0 = qblk * 128 + wid * 32;        // wave owns q [wq0, wq0+32)
        int qg0 = wq0 + qi;
        int qg1 = wq0 + 16 + qi;

        const unsigned short* qp0 = qkv + (size_t)(bb * T_ + qg0) * 3072 + h * 64;
        const unsigned short* qp1 = qkv + (size_t)(bb * T_ + qg1) * 3072 + h * 64;
        bf16x8 qf0a = *(const bf16x8*)(qp0 + g * 8);
        bf16x8 qf0b = *(const bf16x8*)(qp0 + 32 + g * 8);
        bf16x8 qf1a = *(const bf16x8*)(qp1 + g * 8);
        bf16x8 qf1b = *(const bf16x8*)(qp1 + 32 + g * 8);

        f32x4 oacc0[4] = {}, oacc1[4] = {};
        float m0 = -INFINITY, l0 = 0.f, m1 = -INFINITY, l1 = 0.f;
        unsigned short* Pw = &P_l[wid * 32 * 72];

        int ntiles = 2 * qblk + 2;
        for (int t = 0; t < ntiles; ++t) {
            int kt0 = t * 64;
            __syncthreads();      // all waves done reading prev K/Vt
#pragma unroll
            for (int i = 0; i < 2; ++i) {
                int c = tid + i * 256;          // 512 chunks of 8 bf16
                int kr = c >> 3, d8 = c & 7;
                const unsigned short* src =
                    qkv + (size_t)(bb * T_ + kt0 + kr) * 3072 + 1024 + h * 64 + d8 * 8;
                bf16x8 kv = *(const bf16x8*)src;
                bf16x8 vv = *(const bf16x8*)(src + 1024);
                *(bf16x8*)&K_l[kr * 64 + ((d8 ^ (kr & 7)) << 3)] = kv;
                int k8 = kr >> 3, klo = kr & 7;
#pragma unroll
                for (int e = 0; e < 8; ++e)
                    Vt_l[(d8 * 8 + e) * 64 + (((k8 ^ e ^ d8) & 7) << 3) + klo] =
                        (unsigned short)vv[e];
            }
            __syncthreads();
            if (kt0 > wq0 + 31) continue;   // wave fully masked (no barrier inside)
            bool diag = (t >= 2 * qblk);
            attn_qset(K_l, Vt_l, Pw, qf0a, qf0b, m0, l0, oacc0,
                      g, qi, g4, lane, qi, qg0, kt0, diag);
            attn_qset(K_l, Vt_l, Pw, qf1a, qf1b, m1, l1, oacc1,
                      g, qi, g4, lane, 16 + qi, qg1, kt0, diag);
        }

        // ---- epilogue for this half (registers only, no LDS hazard) ----
        float linv0[4], linv1[4];
#pragma unroll
        for (int j = 0; j < 4; ++j) {
            linv0[j] = 1.0f / __shfl(l0, (lane & 48) | (g4 + j));
            linv1[j] = 1.0f / __shfl(l1, (lane & 48) | (g4 + j));
        }
#pragma unroll
        for (int df = 0; df < 4; ++df)
#pragma unroll
            for (int j = 0; j < 4; ++j) {
                int col = h * 64 + df * 16 + qi;
                int qr0 = wq0 + g4 + j;
                int qr1 = wq0 + 16 + g4 + j;
                o[(size_t)(bb * T_ + qr0) * 1024 + col] = f2bf(oacc0[df][j] * linv0[j]);
                o[(size_t)(bb * T_ + qr1) * 1024 + col] = f2bf(oacc1[df][j] * linv1[j]);
            }
    }
}

// ---------------------------------------------------------------------------
// Workspace layout (104 MB peak, all bf16 intermediates):
//   [0,6) wq | [6,8) wo | [8,16) wf1 | [16,24) wf2
//   [24,72) qkv bf16 [8192,3072]  (phase 2: [24,40) ln2 bf16, [40,104) ff bf16)
//   [72,88) h bf16 (ln1 out), then attn out o bf16
//   x1 fp32 lives in d_out; fc2 accumulates into it in place.
// ---------------------------------------------------------------------------
extern "C" void kernel_launch(void* const* d_in, const int* in_sizes, int n_in,
                              void* d_out, int out_size, void* d_ws, size_t ws_size,
                              hipStream_t stream) {
    const float* x     = (const float*)d_in[0];
    const float* ln1_g = (const float*)d_in[1];
    const float* ln1_b = (const float*)d_in[2];
    const float* qkv_w = (const float*)d_in[3];
    const float* qkv_b = (const float*)d_in[4];
    const float* out_w = (const float*)d_in[5];
    const float* out_b = (const float*)d_in[6];
    const float* ln2_g = (const float*)d_in[7];
    const float* ln2_b = (const float*)d_in[8];
    const float* fc1_w = (const float*)d_in[9];
    const float* fc1_b = (const float*)d_in[10];
    const float* fc2_w = (const float*)d_in[11];
    const float* fc2_b = (const float*)d_in[12];
    float* out = (float*)d_out;

    const size_t MB = 1024 * 1024;
    char* wsc = (char*)d_ws;
    unsigned short* wq   = (unsigned short*)(wsc);
    unsigned short* wo   = (unsigned short*)(wsc + 6 * MB);
    unsigned short* wf1  = (unsigned short*)(wsc + 8 * MB);
    unsigned short* wf2  = (unsigned short*)(wsc + 16 * MB);
    unsigned short* qkvb = (unsigned short*)(wsc + 24 * MB);
    unsigned short* hb   = (unsigned short*)(wsc + 72 * MB);
    unsigned short* ln2b = (unsigned short*)(wsc + 24 * MB);
    unsigned short* ffb  = (unsigned short*)(wsc + 40 * MB);

    dim3 blk(256);

    // all four weight converts in one launch
    cvt_all_kernel<<<2048, blk, 0, stream>>>(qkv_w, wq, out_w, wo, fc1_w, wf1, fc2_w, wf2);

    // 1. h = LN1(x) -> bf16
    ln_kernel<<<BT_, blk, 0, stream>>>(x, ln1_g, ln1_b, hb);
    // 2. qkv = h @ qkv_w^T + b -> bf16 [8192,3072]
    gemm_mfma<0, 0, 1><<<dim3(24, 64), blk, 0, stream>>>(hb, wq, qkv_b, nullptr,
                                                         nullptr, qkvb, BT_, 3 * C_, C_);
    // 3. o = attention(qkv) -> bf16
    attn_mfma<<<dim3(8, 64), blk, 0, stream>>>(qkvb, hb);
    // 4. x1 = x + o @ out_w^T + b -> d_out fp32
    gemm_mfma<0, 1, 0><<<dim3(8, 64), blk, 0, stream>>>(hb, wo, out_b, x,
                                                        out, nullptr, BT_, C_, C_);
    // 5. h2 = LN2(x1) -> bf16
    ln_kernel<<<BT_, blk, 0, stream>>>(out, ln2_g, ln2_b, ln2b);
    // 6. ff = gelu(h2 @ fc1_w^T + b) -> bf16 [8192,4096]
    gemm_mfma<1, 0, 1><<<dim3(32, 64), blk, 0, stream>>>(ln2b, wf1, fc1_b, nullptr,
                                                         nullptr, ffb, BT_, FF_, C_);
    // 7. out = x1 + ff @ fc2_w^T + b (in place on d_out)
    gemm_mfma<0, 1, 0><<<dim3(8, 64), blk, 0, stream>>>(ffb, wf2, fc2_b, out,
                                                        out, nullptr, BT_, C_, FF_);
}